// Round 1
// baseline (1015.807 us; speedup 1.0000x reference)
//
#include <hip/hip_runtime.h>
#include <cstdint>

#define N_NODES 100000
#define N_EDGES 1600000
#define NEG_SLOPE 0.2f

// ---------------- CSR build ----------------

__global__ void hist_kernel(const int* __restrict__ dst, int* __restrict__ deg) {
    int i = blockIdx.x * blockDim.x + threadIdx.x;
    int stride = gridDim.x * blockDim.x;
    for (; i < N_EDGES; i += stride) atomicAdd(&deg[dst[i]], 1);
}

#define SCAN_ELEMS 1024   // elements per block (256 threads x 4)
#define SCAN_BLOCKS 98    // ceil(100000/1024)

__global__ void scan_reduce(const int* __restrict__ deg, int* __restrict__ bsum) {
    __shared__ int sd[256];
    int base = blockIdx.x * SCAN_ELEMS;
    int t = threadIdx.x;
    int s = 0;
    #pragma unroll
    for (int j = 0; j < 4; ++j) {
        int idx = base + t * 4 + j;
        if (idx < N_NODES) s += deg[idx];
    }
    sd[t] = s;
    __syncthreads();
    for (int off = 128; off > 0; off >>= 1) {
        if (t < off) sd[t] += sd[t + off];
        __syncthreads();
    }
    if (t == 0) bsum[blockIdx.x] = sd[0];
}

__global__ void scan_bsums(int* __restrict__ bsum, int* __restrict__ rowptr) {
    __shared__ int sd[128];
    int t = threadIdx.x;
    int orig = (t < SCAN_BLOCKS) ? bsum[t] : 0;
    sd[t] = orig;
    __syncthreads();
    for (int off = 1; off < 128; off <<= 1) {
        int x = (t >= off) ? sd[t - off] : 0;
        __syncthreads();
        sd[t] += x;
        __syncthreads();
    }
    if (t < SCAN_BLOCKS) bsum[t] = sd[t] - orig;   // exclusive
    if (t == 0) rowptr[N_NODES] = N_EDGES;
}

__global__ void scan_apply(const int* __restrict__ deg, const int* __restrict__ bexcl,
                           int* __restrict__ rowptr, int* __restrict__ cursor) {
    __shared__ int sd[256];
    int base = blockIdx.x * SCAN_ELEMS;
    int t = threadIdx.x;
    int v[4]; int s = 0;
    #pragma unroll
    for (int j = 0; j < 4; ++j) {
        int idx = base + t * 4 + j;
        v[j] = (idx < N_NODES) ? deg[idx] : 0;
        s += v[j];
    }
    sd[t] = s;
    __syncthreads();
    for (int off = 1; off < 256; off <<= 1) {
        int x = (t >= off) ? sd[t - off] : 0;
        __syncthreads();
        sd[t] += x;
        __syncthreads();
    }
    int run = bexcl[blockIdx.x] + (sd[t] - s);
    #pragma unroll
    for (int j = 0; j < 4; ++j) {
        int idx = base + t * 4 + j;
        if (idx < N_NODES) { rowptr[idx] = run; cursor[idx] = run; }
        run += v[j];
    }
}

__global__ void scatter_csr(const int* __restrict__ src, const int* __restrict__ dst,
                            int* __restrict__ cursor, int* __restrict__ csr) {
    int i = blockIdx.x * blockDim.x + threadIdx.x;
    int stride = gridDim.x * blockDim.x;
    for (; i < N_EDGES; i += stride) {
        int d = dst[i];
        int pos = atomicAdd(&cursor[d], 1);
        csr[pos] = src[i];
    }
}

// ---------------- GEMM (NC = 128) ----------------
// BM=32, BN=128, BK=32, block 256 threads, 4x4 register blocking.

template <int K>
__global__ __launch_bounds__(256) void gemm_nc128(const float* __restrict__ X,
                                                  const float* __restrict__ W,
                                                  float* __restrict__ Y) {
    __shared__ float Xs[32][36];    // transposed: Xs[k][m], pad keeps float4 align + bank rotate
    __shared__ float Ws[32][128];
    int m0 = blockIdx.x * 32;
    int t = threadIdx.x;
    int rg = t >> 5;        // 0..7  (4 rows each)
    int cg = t & 31;        // 0..31 (float4 col group)
    float4 acc[4];
    #pragma unroll
    for (int i = 0; i < 4; ++i) acc[i] = make_float4(0.f, 0.f, 0.f, 0.f);

    for (int kt = 0; kt < K; kt += 32) {
        {   // X tile 32x32 -> transposed LDS
            int m = t >> 3, k4 = (t & 7) << 2;
            float4 xv = *reinterpret_cast<const float4*>(&X[(size_t)(m0 + m) * K + kt + k4]);
            Xs[k4 + 0][m] = xv.x; Xs[k4 + 1][m] = xv.y;
            Xs[k4 + 2][m] = xv.z; Xs[k4 + 3][m] = xv.w;
        }
        #pragma unroll
        for (int j = 0; j < 4; ++j) {   // W tile 32x128
            int idx = t + (j << 8);
            int r = idx >> 5, c4 = (idx & 31) << 2;
            *reinterpret_cast<float4*>(&Ws[r][c4]) =
                *reinterpret_cast<const float4*>(&W[(size_t)(kt + r) * 128 + c4]);
        }
        __syncthreads();
        #pragma unroll
        for (int kk = 0; kk < 32; ++kk) {
            float4 w = *reinterpret_cast<const float4*>(&Ws[kk][cg << 2]);
            float4 xq = *reinterpret_cast<const float4*>(&Xs[kk][rg << 2]);
            acc[0].x += xq.x * w.x; acc[0].y += xq.x * w.y; acc[0].z += xq.x * w.z; acc[0].w += xq.x * w.w;
            acc[1].x += xq.y * w.x; acc[1].y += xq.y * w.y; acc[1].z += xq.y * w.z; acc[1].w += xq.y * w.w;
            acc[2].x += xq.z * w.x; acc[2].y += xq.z * w.y; acc[2].z += xq.z * w.z; acc[2].w += xq.z * w.w;
            acc[3].x += xq.w * w.x; acc[3].y += xq.w * w.y; acc[3].z += xq.w * w.z; acc[3].w += xq.w * w.w;
        }
        __syncthreads();
    }
    #pragma unroll
    for (int i = 0; i < 4; ++i)
        *reinterpret_cast<float4*>(&Y[(size_t)(m0 + (rg << 2) + i) * 128 + (cg << 2)]) = acc[i];
}

// ---------------- GEMM (K=128, NC=40) ----------------

__global__ __launch_bounds__(256) void gemm_nc40(const float* __restrict__ X,
                                                 const float* __restrict__ W,
                                                 float* __restrict__ Y) {
    __shared__ float Xs[64][132];   // pad 132: float4-aligned rows, bank rotate
    __shared__ float Ws[128][40];
    int m0 = blockIdx.x * 64;
    int t = threadIdx.x;
    for (int idx = t; idx < 128 * 40; idx += 256) Ws[idx / 40][idx % 40] = W[idx];
    for (int q = t; q < 2048; q += 256) {
        int r = q >> 5;
        int c4 = (q & 31) << 2;
        int row = m0 + r;
        float4 xv = (row < N_NODES)
            ? *reinterpret_cast<const float4*>(&X[(size_t)row * 128 + c4])
            : make_float4(0.f, 0.f, 0.f, 0.f);
        *reinterpret_cast<float4*>(&Xs[r][c4]) = xv;
    }
    __syncthreads();
    int r = t >> 2;          // 0..63
    int cq = t & 3;          // 0..3 -> 10 cols each
    float acc[10];
    #pragma unroll
    for (int j = 0; j < 10; ++j) acc[j] = 0.f;
    for (int k = 0; k < 128; ++k) {
        float xv = Xs[r][k];
        #pragma unroll
        for (int j = 0; j < 10; ++j) acc[j] += xv * Ws[k][cq * 10 + j];
    }
    int row = m0 + r;
    if (row < N_NODES) {
        #pragma unroll
        for (int j = 0; j < 10; ++j) Y[(size_t)row * 40 + cq * 10 + j] = acc[j];
    }
}

// ---------------- per-node attention coefficients ----------------
// wave per node; lane owns cols 2l, 2l+1. SEG lanes per head reduce.

template <int WD, int NH, int SEG>
__global__ void as_ad_kernel(const float* __restrict__ XH, const float* __restrict__ asrc,
                             const float* __restrict__ adst, float* __restrict__ As,
                             float* __restrict__ Ad) {
    int node = (int)((blockIdx.x * blockDim.x + threadIdx.x) >> 6);
    int lane = threadIdx.x & 63;
    if (node >= N_NODES) return;
    int c0 = lane * 2;
    float s = 0.f, d = 0.f;
    if (c0 < WD) {
        float2 x = *reinterpret_cast<const float2*>(&XH[(size_t)node * WD + c0]);
        float2 a = *reinterpret_cast<const float2*>(&asrc[c0]);
        float2 b = *reinterpret_cast<const float2*>(&adst[c0]);
        s = x.x * a.x + x.y * a.y;
        d = x.x * b.x + x.y * b.y;
    }
    #pragma unroll
    for (int off = 1; off < SEG; off <<= 1) {
        s += __shfl_xor(s, off, 64);
        d += __shfl_xor(d, off, 64);
    }
    if ((lane % SEG) == 0 && c0 < WD) {
        int h = c0 / (WD / NH);
        As[(size_t)node * NH + h] = s;
        Ad[(size_t)node * NH + h] = d;
    }
}

// ---------------- aggregation: online softmax over incoming edges ----------------

template <int WD, int NH, bool RELU>
__global__ void aggregate_kernel(const float* __restrict__ XH, const float* __restrict__ As,
                                 const float* __restrict__ Ad, const float* __restrict__ bias,
                                 const int* __restrict__ rowptr, const int* __restrict__ csr,
                                 float* __restrict__ Y) {
    int node = (int)((blockIdx.x * blockDim.x + threadIdx.x) >> 6);
    int lane = threadIdx.x & 63;
    if (node >= N_NODES) return;
    constexpr int NC = WD / NH;
    int c0 = lane * 2;
    int h = (c0 < WD) ? (c0 / NC) : 0;
    float adi = Ad[(size_t)node * NH + h];
    int beg = rowptr[node], end = rowptr[node + 1];
    float m = -1e30f, den = 0.f, a0 = 0.f, a1 = 0.f;
    for (int j = beg; j <= end; ++j) {
        int src = (j == end) ? node : csr[j];
        float e = As[(size_t)src * NH + h] + adi;
        e = (e > 0.f) ? e : NEG_SLOPE * e;
        float nm = fmaxf(m, e);
        float f = __expf(m - nm);
        float p = __expf(e - nm);
        den = den * f + p;
        float2 x = make_float2(0.f, 0.f);
        if (c0 < WD) x = *reinterpret_cast<const float2*>(&XH[(size_t)src * WD + c0]);
        a0 = a0 * f + p * x.x;
        a1 = a1 * f + p * x.y;
        m = nm;
    }
    if (c0 < WD) {
        float inv = 1.0f / den;
        float o0 = a0 * inv + bias[c0];
        float o1 = a1 * inv + bias[c0 + 1];
        if (RELU) { o0 = fmaxf(o0, 0.f); o1 = fmaxf(o1, 0.f); }
        float2 o = make_float2(o0, o1);
        *reinterpret_cast<float2*>(&Y[(size_t)node * WD + c0]) = o;
    }
}

// ---------------- log-softmax over 40 classes ----------------

__global__ void logsoftmax_kernel(float* __restrict__ Y) {
    int node = (int)((blockIdx.x * blockDim.x + threadIdx.x) >> 6);
    int lane = threadIdx.x & 63;
    if (node >= N_NODES) return;
    float v = (lane < 40) ? Y[(size_t)node * 40 + lane] : -1e30f;
    float mm = v;
    #pragma unroll
    for (int off = 1; off < 64; off <<= 1) mm = fmaxf(mm, __shfl_xor(mm, off, 64));
    float p = (lane < 40) ? __expf(v - mm) : 0.f;
    #pragma unroll
    for (int off = 1; off < 64; off <<= 1) p += __shfl_xor(p, off, 64);
    float r = v - mm - __logf(p);
    if (lane < 40) Y[(size_t)node * 40 + lane] = r;
}

// ---------------- launch ----------------

extern "C" void kernel_launch(void* const* d_in, const int* in_sizes, int n_in,
                              void* d_out, int out_size, void* d_ws, size_t ws_size,
                              hipStream_t stream) {
    const int*   edge = (const int*)d_in[0];
    const float* feat = (const float*)d_in[1];
    const float* W1   = (const float*)d_in[2];
    const float* as1  = (const float*)d_in[3];
    const float* ad1  = (const float*)d_in[4];
    const float* b1   = (const float*)d_in[5];
    const float* W2   = (const float*)d_in[6];
    const float* as2  = (const float*)d_in[7];
    const float* ad2  = (const float*)d_in[8];
    const float* b2   = (const float*)d_in[9];
    const float* W3   = (const float*)d_in[10];
    const float* as3  = (const float*)d_in[11];
    const float* ad3  = (const float*)d_in[12];
    const float* b3   = (const float*)d_in[13];
    float* out = (float*)d_out;

    const int* srcArr = edge;
    const int* dstArr = edge + N_EDGES;

    char* w = (char*)d_ws;
    float* buf0 = (float*)w;  w += (size_t)N_NODES * 128 * 4;
    float* buf1 = (float*)w;  w += (size_t)N_NODES * 128 * 4;
    float* As   = (float*)w;  w += (size_t)N_NODES * 4 * 4;
    float* Ad   = (float*)w;  w += (size_t)N_NODES * 4 * 4;
    int* rowptr = (int*)w;    w += (size_t)(N_NODES + 1) * 4;
    int* cursor = (int*)w;    w += (size_t)N_NODES * 4;
    int* deg    = (int*)w;    w += (size_t)N_NODES * 4;
    int* bsum   = (int*)w;    w += (size_t)256 * 4;
    int* csr    = (int*)w;    w += (size_t)N_EDGES * 4;

    hipMemsetAsync(deg, 0, (size_t)N_NODES * 4, stream);
    hist_kernel<<<512, 256, 0, stream>>>(dstArr, deg);
    scan_reduce<<<SCAN_BLOCKS, 256, 0, stream>>>(deg, bsum);
    scan_bsums<<<1, 128, 0, stream>>>(bsum, rowptr);
    scan_apply<<<SCAN_BLOCKS, 256, 0, stream>>>(deg, bsum, rowptr, cursor);
    scatter_csr<<<512, 256, 0, stream>>>(srcArr, dstArr, cursor, csr);

    int aggGrid = (N_NODES + 3) / 4;   // 4 waves (nodes) per 256-thread block

    // ---- layer 1: 256 -> 4x32, relu ----
    gemm_nc128<256><<<3125, 256, 0, stream>>>(feat, W1, buf0);
    as_ad_kernel<128, 4, 16><<<aggGrid, 256, 0, stream>>>(buf0, as1, ad1, As, Ad);
    aggregate_kernel<128, 4, true><<<aggGrid, 256, 0, stream>>>(buf0, As, Ad, b1, rowptr, csr, buf1);

    // ---- layer 2: 128 -> 128, relu ----
    gemm_nc128<128><<<3125, 256, 0, stream>>>(buf1, W2, buf0);
    as_ad_kernel<128, 1, 64><<<aggGrid, 256, 0, stream>>>(buf0, as2, ad2, As, Ad);
    aggregate_kernel<128, 1, true><<<aggGrid, 256, 0, stream>>>(buf0, As, Ad, b2, rowptr, csr, buf1);

    // ---- layer 3: 128 -> 40 ----
    gemm_nc40<<<1563, 256, 0, stream>>>(buf1, W3, buf0);
    as_ad_kernel<40, 1, 64><<<aggGrid, 256, 0, stream>>>(buf0, as3, ad3, As, Ad);
    aggregate_kernel<40, 1, false><<<aggGrid, 256, 0, stream>>>(buf0, As, Ad, b3, rowptr, csr, out);
    logsoftmax_kernel<<<aggGrid, 256, 0, stream>>>(out);
}

// Round 3
// 884.278 us; speedup vs baseline: 1.1487x; 1.1487x over previous
//
#include <hip/hip_runtime.h>
#include <cstdint>

#define N_NODES 100000
#define N_EDGES 1600000
#define NEG_SLOPE 0.2f

typedef short s16x8 __attribute__((ext_vector_type(8)));
typedef float f32x4 __attribute__((ext_vector_type(4)));

__device__ inline float bf2f(ushort u) {
    union { uint i; float f; } x; x.i = ((uint)u) << 16; return x.f;
}
__device__ inline ushort f2bf(float f) {
    union { float f; uint i; } x; x.f = f;
    uint r = x.i + 0x7FFF + ((x.i >> 16) & 1);   // RNE
    return (ushort)(r >> 16);
}

// ---------------- CSR build ----------------

__global__ void hist_kernel(const int* __restrict__ dst, int* __restrict__ deg) {
    int i = blockIdx.x * blockDim.x + threadIdx.x;
    int stride = gridDim.x * blockDim.x;
    for (; i < N_EDGES; i += stride) atomicAdd(&deg[dst[i]], 1);
}

#define SCAN_ELEMS 1024
#define SCAN_BLOCKS 98

__global__ void scan_reduce(const int* __restrict__ deg, int* __restrict__ bsum) {
    __shared__ int sd[256];
    int base = blockIdx.x * SCAN_ELEMS;
    int t = threadIdx.x;
    int s = 0;
    #pragma unroll
    for (int j = 0; j < 4; ++j) {
        int idx = base + t * 4 + j;
        if (idx < N_NODES) s += deg[idx];
    }
    sd[t] = s;
    __syncthreads();
    for (int off = 128; off > 0; off >>= 1) {
        if (t < off) sd[t] += sd[t + off];
        __syncthreads();
    }
    if (t == 0) bsum[blockIdx.x] = sd[0];
}

__global__ void scan_bsums(int* __restrict__ bsum, int* __restrict__ rowptr) {
    __shared__ int sd[128];
    int t = threadIdx.x;
    int orig = (t < SCAN_BLOCKS) ? bsum[t] : 0;
    sd[t] = orig;
    __syncthreads();
    for (int off = 1; off < 128; off <<= 1) {
        int x = (t >= off) ? sd[t - off] : 0;
        __syncthreads();
        sd[t] += x;
        __syncthreads();
    }
    if (t < SCAN_BLOCKS) bsum[t] = sd[t] - orig;   // exclusive
    if (t == 0) rowptr[N_NODES] = N_EDGES;
}

__global__ void scan_apply(const int* __restrict__ deg, const int* __restrict__ bexcl,
                           int* __restrict__ rowptr, int* __restrict__ cursor) {
    __shared__ int sd[256];
    int base = blockIdx.x * SCAN_ELEMS;
    int t = threadIdx.x;
    int v[4]; int s = 0;
    #pragma unroll
    for (int j = 0; j < 4; ++j) {
        int idx = base + t * 4 + j;
        v[j] = (idx < N_NODES) ? deg[idx] : 0;
        s += v[j];
    }
    sd[t] = s;
    __syncthreads();
    for (int off = 1; off < 256; off <<= 1) {
        int x = (t >= off) ? sd[t - off] : 0;
        __syncthreads();
        sd[t] += x;
        __syncthreads();
    }
    int run = bexcl[blockIdx.x] + (sd[t] - s);
    #pragma unroll
    for (int j = 0; j < 4; ++j) {
        int idx = base + t * 4 + j;
        if (idx < N_NODES) { rowptr[idx] = run; cursor[idx] = run; }
        run += v[j];
    }
}

__global__ void scatter_csr(const int* __restrict__ src, const int* __restrict__ dst,
                            int* __restrict__ cursor, int* __restrict__ csr) {
    int i = blockIdx.x * blockDim.x + threadIdx.x;
    int stride = gridDim.x * blockDim.x;
    for (; i < N_EDGES; i += stride) {
        int d = dst[i];
        int pos = atomicAdd(&cursor[d], 1);
        csr[pos] = src[i];
    }
}

// ---------------- converts ----------------

__global__ void convert_bf16(const float* __restrict__ X, ushort* __restrict__ Y, int n8) {
    int i = blockIdx.x * blockDim.x + threadIdx.x;   // one thread = 8 elements
    if (i >= n8) return;
    float4 a = reinterpret_cast<const float4*>(X)[i * 2];
    float4 b = reinterpret_cast<const float4*>(X)[i * 2 + 1];
    ushort o[8] = { f2bf(a.x), f2bf(a.y), f2bf(a.z), f2bf(a.w),
                    f2bf(b.x), f2bf(b.y), f2bf(b.z), f2bf(b.w) };
    reinterpret_cast<uint4*>(Y)[i] = *reinterpret_cast<uint4*>(o);
}

// W [K][N] fp32 -> BT [Npad][K] bf16 (zero pad rows n>=N)
__global__ void transpose_w(const float* __restrict__ W, ushort* __restrict__ BT,
                            int K, int N, int Npad) {
    int i = blockIdx.x * blockDim.x + threadIdx.x;
    if (i >= Npad * K) return;
    int n = i / K, k = i - n * K;
    float v = (n < N) ? W[(size_t)k * N + n] : 0.f;
    BT[i] = f2bf(v);
}

// ---------------- MFMA GEMM, N=128 out bf16 ----------------
// BM=64, BN=128, BK=32; 4 waves 2x2; wave tile 32x64 = 2x4 frags of 16x16.

template <int K>
__global__ __launch_bounds__(256) void mfma_gemm_nc128(const ushort* __restrict__ X,
                                                       const ushort* __restrict__ BT,
                                                       ushort* __restrict__ Y) {
    __shared__ ushort As[64][40];
    __shared__ ushort Bs[128][40];
    int m0 = blockIdx.x * 64;
    int t = threadIdx.x;
    int wave = t >> 6, lane = t & 63;
    int wm = wave >> 1, wn = wave & 1;
    f32x4 acc[2][4] = {};
    for (int kt = 0; kt < K; kt += 32) {
        {
            int r = t >> 2, kg = (t & 3) << 3;
            *(s16x8*)&As[r][kg] = *(const s16x8*)&X[(size_t)(m0 + r) * K + kt + kg];
        }
        #pragma unroll
        for (int i = 0; i < 2; ++i) {
            int idx = t + (i << 8);
            int r = idx >> 2, kg = (idx & 3) << 3;
            *(s16x8*)&Bs[r][kg] = *(const s16x8*)&BT[(size_t)r * K + kt + kg];
        }
        __syncthreads();
        int row = lane & 15, koff = (lane >> 4) << 3;
        s16x8 a[2], b[4];
        #pragma unroll
        for (int mf = 0; mf < 2; ++mf)
            a[mf] = *(s16x8*)&As[wm * 32 + mf * 16 + row][koff];
        #pragma unroll
        for (int nf = 0; nf < 4; ++nf)
            b[nf] = *(s16x8*)&Bs[wn * 64 + nf * 16 + row][koff];
        #pragma unroll
        for (int mf = 0; mf < 2; ++mf)
            #pragma unroll
            for (int nf = 0; nf < 4; ++nf)
                acc[mf][nf] = __builtin_amdgcn_mfma_f32_16x16x32_bf16(a[mf], b[nf], acc[mf][nf], 0, 0, 0);
        __syncthreads();
    }
    int colb = lane & 15, rowb = (lane >> 4) << 2;
    #pragma unroll
    for (int mf = 0; mf < 2; ++mf)
        #pragma unroll
        for (int nf = 0; nf < 4; ++nf)
            #pragma unroll
            for (int reg = 0; reg < 4; ++reg) {
                int row = m0 + wm * 32 + mf * 16 + rowb + reg;
                int col = wn * 64 + nf * 16 + colb;
                if (row < N_NODES) Y[(size_t)row * 128 + col] = f2bf(acc[mf][nf][reg]);
            }
}

// ---------------- MFMA GEMM, K=128, N=40 (padded 48), out fp32 ----------------

__global__ __launch_bounds__(256) void mfma_gemm_nc40(const ushort* __restrict__ X,
                                                      const ushort* __restrict__ BT,
                                                      float* __restrict__ Y) {
    __shared__ ushort As[64][40];
    __shared__ ushort Bs[48][40];
    int m0 = blockIdx.x * 64;
    int t = threadIdx.x, wave = t >> 6, lane = t & 63;
    f32x4 acc[3] = {};
    for (int kt = 0; kt < 128; kt += 32) {
        {
            int r = t >> 2, kg = (t & 3) << 3;
            *(s16x8*)&As[r][kg] = *(const s16x8*)&X[(size_t)(m0 + r) * 128 + kt + kg];
        }
        if (t < 192) {
            int r = t >> 2, kg = (t & 3) << 3;
            *(s16x8*)&Bs[r][kg] = *(const s16x8*)&BT[(size_t)r * 128 + kt + kg];
        }
        __syncthreads();
        int row = lane & 15, koff = (lane >> 4) << 3;
        s16x8 a = *(s16x8*)&As[wave * 16 + row][koff];
        #pragma unroll
        for (int nf = 0; nf < 3; ++nf) {
            s16x8 b = *(s16x8*)&Bs[nf * 16 + row][koff];
            acc[nf] = __builtin_amdgcn_mfma_f32_16x16x32_bf16(a, b, acc[nf], 0, 0, 0);
        }
        __syncthreads();
    }
    int colb = lane & 15, rowb = (lane >> 4) << 2;
    #pragma unroll
    for (int nf = 0; nf < 3; ++nf)
        #pragma unroll
        for (int reg = 0; reg < 4; ++reg) {
            int row = m0 + wave * 16 + rowb + reg;
            int col = nf * 16 + colb;
            if (row < N_NODES && col < 40) Y[(size_t)row * 40 + col] = acc[nf][reg];
        }
}

// ---------------- attention coefficients ----------------

template <int WD, int NH, int SEG>
__global__ void as_ad_bf16(const ushort* __restrict__ XH, const float* __restrict__ asrc,
                           const float* __restrict__ adst, float* __restrict__ As,
                           float* __restrict__ Ad) {
    int node = (int)((blockIdx.x * blockDim.x + threadIdx.x) >> 6);
    int lane = threadIdx.x & 63;
    if (node >= N_NODES) return;
    int c0 = lane * 2;
    uint xv = *reinterpret_cast<const uint*>(&XH[(size_t)node * WD + c0]);
    float x0 = bf2f((ushort)(xv & 0xFFFF)), x1 = bf2f((ushort)(xv >> 16));
    float2 a = *reinterpret_cast<const float2*>(&asrc[c0]);
    float2 b = *reinterpret_cast<const float2*>(&adst[c0]);
    float s = x0 * a.x + x1 * a.y;
    float d = x0 * b.x + x1 * b.y;
    #pragma unroll
    for (int off = 1; off < SEG; off <<= 1) {
        s += __shfl_xor(s, off, 64);
        d += __shfl_xor(d, off, 64);
    }
    if ((lane % SEG) == 0) {
        int h = c0 / (WD / NH);
        As[(size_t)node * NH + h] = s;
        Ad[(size_t)node * NH + h] = d;
    }
}

template <int WD, int NH, int SEG>
__global__ void as_ad_f32(const float* __restrict__ XH, const float* __restrict__ asrc,
                          const float* __restrict__ adst, float* __restrict__ As,
                          float* __restrict__ Ad) {
    int node = (int)((blockIdx.x * blockDim.x + threadIdx.x) >> 6);
    int lane = threadIdx.x & 63;
    if (node >= N_NODES) return;
    int c0 = lane * 2;
    float s = 0.f, d = 0.f;
    if (c0 < WD) {
        float2 x = *reinterpret_cast<const float2*>(&XH[(size_t)node * WD + c0]);
        float2 a = *reinterpret_cast<const float2*>(&asrc[c0]);
        float2 b = *reinterpret_cast<const float2*>(&adst[c0]);
        s = x.x * a.x + x.y * a.y;
        d = x.x * b.x + x.y * b.y;
    }
    #pragma unroll
    for (int off = 1; off < SEG; off <<= 1) {
        s += __shfl_xor(s, off, 64);
        d += __shfl_xor(d, off, 64);
    }
    if ((lane % SEG) == 0 && c0 < WD) {
        int h = c0 / (WD / NH);
        As[(size_t)node * NH + h] = s;
        Ad[(size_t)node * NH + h] = d;
    }
}

// ---------------- aggregation: online softmax ----------------

// bf16 in, bf16 out (+relu). WD=128 only.
template <int WD, int NH>
__global__ void aggregate_bf16(const ushort* __restrict__ XH, const float* __restrict__ As,
                               const float* __restrict__ Ad, const float* __restrict__ bias,
                               const int* __restrict__ rowptr, const int* __restrict__ csr,
                               ushort* __restrict__ Y) {
    int node = (int)((blockIdx.x * blockDim.x + threadIdx.x) >> 6);
    int lane = threadIdx.x & 63;
    if (node >= N_NODES) return;
    constexpr int NC = WD / NH;
    int c0 = lane * 2;
    int h = c0 / NC;
    float adi = Ad[(size_t)node * NH + h];
    int beg = rowptr[node], end = rowptr[node + 1];
    float m = -1e30f, den = 0.f, a0 = 0.f, a1 = 0.f;
    for (int j = beg; j <= end; ++j) {
        int src = (j == end) ? node : csr[j];
        float e = As[(size_t)src * NH + h] + adi;
        e = (e > 0.f) ? e : NEG_SLOPE * e;
        float nm = fmaxf(m, e);
        float f = __expf(m - nm);
        float p = __expf(e - nm);
        den = den * f + p;
        uint xv = *reinterpret_cast<const uint*>(&XH[(size_t)src * WD + c0]);
        a0 = a0 * f + p * bf2f((ushort)(xv & 0xFFFF));
        a1 = a1 * f + p * bf2f((ushort)(xv >> 16));
        m = nm;
    }
    float inv = 1.0f / den;
    float o0 = fmaxf(a0 * inv + bias[c0], 0.f);
    float o1 = fmaxf(a1 * inv + bias[c0 + 1], 0.f);
    uint packed = (uint)f2bf(o0) | ((uint)f2bf(o1) << 16);
    *reinterpret_cast<uint*>(&Y[(size_t)node * WD + c0]) = packed;
}

// fp32 in/out (layer 3)
template <int WD, int NH, bool RELU>
__global__ void aggregate_f32(const float* __restrict__ XH, const float* __restrict__ As,
                              const float* __restrict__ Ad, const float* __restrict__ bias,
                              const int* __restrict__ rowptr, const int* __restrict__ csr,
                              float* __restrict__ Y) {
    int node = (int)((blockIdx.x * blockDim.x + threadIdx.x) >> 6);
    int lane = threadIdx.x & 63;
    if (node >= N_NODES) return;
    constexpr int NC = WD / NH;
    int c0 = lane * 2;
    int h = (c0 < WD) ? (c0 / NC) : 0;
    float adi = Ad[(size_t)node * NH + h];
    int beg = rowptr[node], end = rowptr[node + 1];
    float m = -1e30f, den = 0.f, a0 = 0.f, a1 = 0.f;
    for (int j = beg; j <= end; ++j) {
        int src = (j == end) ? node : csr[j];
        float e = As[(size_t)src * NH + h] + adi;
        e = (e > 0.f) ? e : NEG_SLOPE * e;
        float nm = fmaxf(m, e);
        float f = __expf(m - nm);
        float p = __expf(e - nm);
        den = den * f + p;
        float2 x = make_float2(0.f, 0.f);
        if (c0 < WD) x = *reinterpret_cast<const float2*>(&XH[(size_t)src * WD + c0]);
        a0 = a0 * f + p * x.x;
        a1 = a1 * f + p * x.y;
        m = nm;
    }
    if (c0 < WD) {
        float inv = 1.0f / den;
        float o0 = a0 * inv + bias[c0];
        float o1 = a1 * inv + bias[c0 + 1];
        if (RELU) { o0 = fmaxf(o0, 0.f); o1 = fmaxf(o1, 0.f); }
        *reinterpret_cast<float2*>(&Y[(size_t)node * WD + c0]) = make_float2(o0, o1);
    }
}

// ---------------- log-softmax over 40 classes ----------------

__global__ void logsoftmax_kernel(float* __restrict__ Y) {
    int node = (int)((blockIdx.x * blockDim.x + threadIdx.x) >> 6);
    int lane = threadIdx.x & 63;
    if (node >= N_NODES) return;
    float v = (lane < 40) ? Y[(size_t)node * 40 + lane] : -1e30f;
    float mm = v;
    #pragma unroll
    for (int off = 1; off < 64; off <<= 1) mm = fmaxf(mm, __shfl_xor(mm, off, 64));
    float p = (lane < 40) ? __expf(v - mm) : 0.f;
    #pragma unroll
    for (int off = 1; off < 64; off <<= 1) p += __shfl_xor(p, off, 64);
    float r = v - mm - __logf(p);
    if (lane < 40) Y[(size_t)node * 40 + lane] = r;
}

// ---------------- launch ----------------

static inline size_t align256(size_t x) { return (x + 255) & ~(size_t)255; }

extern "C" void kernel_launch(void* const* d_in, const int* in_sizes, int n_in,
                              void* d_out, int out_size, void* d_ws, size_t ws_size,
                              hipStream_t stream) {
    const int*   edge = (const int*)d_in[0];
    const float* feat = (const float*)d_in[1];
    const float* W1   = (const float*)d_in[2];
    const float* as1  = (const float*)d_in[3];
    const float* ad1  = (const float*)d_in[4];
    const float* b1   = (const float*)d_in[5];
    const float* W2   = (const float*)d_in[6];
    const float* as2  = (const float*)d_in[7];
    const float* ad2  = (const float*)d_in[8];
    const float* b2   = (const float*)d_in[9];
    const float* W3   = (const float*)d_in[10];
    const float* as3  = (const float*)d_in[11];
    const float* ad3  = (const float*)d_in[12];
    const float* b3   = (const float*)d_in[13];
    float* out = (float*)d_out;

    const int* srcArr = edge;
    const int* dstArr = edge + N_EDGES;

    const size_t NB128 = (size_t)N_NODES * 128 * 2;   // bf16 [N][128]

    char* w = (char*)d_ws;
    char* regionA = w; w += align256(2 * NB128);      // Xbf (51.2MB); later xh2|h2
    char* regionB = w; w += align256(2 * NB128 / 2);  // xh1 (25.6MB); later xh3 fp32 (16MB)
    char* regionC = w; w += align256(NB128);          // h1 (25.6MB)
    float* As   = (float*)w; w += align256((size_t)N_NODES * 4 * 4);
    float* Ad   = (float*)w; w += align256((size_t)N_NODES * 4 * 4);
    int* rowptr = (int*)w;   w += align256((size_t)(N_NODES + 1) * 4);
    int* cursor = (int*)w;   w += align256((size_t)N_NODES * 4);
    int* deg    = (int*)w;   w += align256((size_t)N_NODES * 4);
    int* bsum   = (int*)w;   w += align256((size_t)256 * 4);
    int* csr    = (int*)w;   w += align256((size_t)N_EDGES * 4);
    ushort* WT1 = (ushort*)w; w += align256((size_t)128 * 256 * 2);
    ushort* WT2 = (ushort*)w; w += align256((size_t)128 * 128 * 2);
    ushort* WT3 = (ushort*)w; w += align256((size_t)48 * 128 * 2);

    ushort* Xbf = (ushort*)regionA;                   // [100k][256]
    ushort* xh1 = (ushort*)regionB;                   // [100k][128]
    ushort* h1  = (ushort*)regionC;                   // [100k][128]
    ushort* xh2 = (ushort*)regionA;                   // [100k][128]
    ushort* h2  = (ushort*)(regionA + NB128);         // [100k][128]
    float*  xh3 = (float*)regionB;                    // [100k][40]

    // CSR
    hipMemsetAsync(deg, 0, (size_t)N_NODES * 4, stream);
    hist_kernel<<<512, 256, 0, stream>>>(dstArr, deg);
    scan_reduce<<<SCAN_BLOCKS, 256, 0, stream>>>(deg, bsum);
    scan_bsums<<<1, 128, 0, stream>>>(bsum, rowptr);
    scan_apply<<<SCAN_BLOCKS, 256, 0, stream>>>(deg, bsum, rowptr, cursor);
    scatter_csr<<<512, 256, 0, stream>>>(srcArr, dstArr, cursor, csr);

    // converts
    convert_bf16<<<(N_NODES * 256 / 8 + 255) / 256, 256, 0, stream>>>(feat, Xbf, N_NODES * 256 / 8);
    transpose_w<<<(128 * 256 + 255) / 256, 256, 0, stream>>>(W1, WT1, 256, 128, 128);
    transpose_w<<<(128 * 128 + 255) / 256, 256, 0, stream>>>(W2, WT2, 128, 128, 128);
    transpose_w<<<(48 * 128 + 255) / 256, 256, 0, stream>>>(W3, WT3, 128, 40, 48);

    int aggGrid = (N_NODES + 3) / 4;
    int gemmGrid = (N_NODES + 63) / 64;

    // ---- layer 1: 256 -> 4x32, relu ----
    mfma_gemm_nc128<256><<<gemmGrid, 256, 0, stream>>>(Xbf, WT1, xh1);
    as_ad_bf16<128, 4, 16><<<aggGrid, 256, 0, stream>>>(xh1, as1, ad1, As, Ad);
    aggregate_bf16<128, 4><<<aggGrid, 256, 0, stream>>>(xh1, As, Ad, b1, rowptr, csr, h1);

    // ---- layer 2: 128 -> 128, relu ----
    mfma_gemm_nc128<128><<<gemmGrid, 256, 0, stream>>>(h1, WT2, xh2);
    as_ad_bf16<128, 1, 64><<<aggGrid, 256, 0, stream>>>(xh2, as2, ad2, As, Ad);
    aggregate_bf16<128, 1><<<aggGrid, 256, 0, stream>>>(xh2, As, Ad, b2, rowptr, csr, h2);

    // ---- layer 3: 128 -> 40 ----
    mfma_gemm_nc40<<<gemmGrid, 256, 0, stream>>>(h2, WT3, xh3);
    as_ad_f32<40, 1, 64><<<aggGrid, 256, 0, stream>>>(xh3, as3, ad3, As, Ad);
    aggregate_f32<40, 1, false><<<aggGrid, 256, 0, stream>>>(xh3, As, Ad, b3, rowptr, csr, out);
    logsoftmax_kernel<<<aggGrid, 256, 0, stream>>>(out);
}

// Round 4
// 660.139 us; speedup vs baseline: 1.5388x; 1.3395x over previous
//
#include <hip/hip_runtime.h>
#include <cstdint>

#define N_NODES 100000
#define N_EDGES 1600000
#define NEG_SLOPE 0.2f

typedef short s16x8 __attribute__((ext_vector_type(8)));
typedef float f32x4 __attribute__((ext_vector_type(4)));

__device__ inline float bf2f(ushort u) {
    union { uint i; float f; } x; x.i = ((uint)u) << 16; return x.f;
}
__device__ inline ushort f2bf(float f) {
    union { float f; uint i; } x; x.f = f;
    uint r = x.i + 0x7FFF + ((x.i >> 16) & 1);   // RNE
    return (ushort)(r >> 16);
}
__device__ inline float lrelu(float e) { return (e > 0.f) ? e : NEG_SLOPE * e; }

// ---------------- CSR build ----------------

__global__ void hist_kernel(const int* __restrict__ dst, int* __restrict__ deg) {
    int i = blockIdx.x * blockDim.x + threadIdx.x;
    int stride = gridDim.x * blockDim.x;
    for (; i < N_EDGES; i += stride) atomicAdd(&deg[dst[i]], 1);
}

#define SCAN_ELEMS 1024
#define SCAN_BLOCKS 98

__global__ void scan_reduce(const int* __restrict__ deg, int* __restrict__ bsum) {
    __shared__ int sd[256];
    int base = blockIdx.x * SCAN_ELEMS;
    int t = threadIdx.x;
    int s = 0;
    #pragma unroll
    for (int j = 0; j < 4; ++j) {
        int idx = base + t * 4 + j;
        if (idx < N_NODES) s += deg[idx];
    }
    sd[t] = s;
    __syncthreads();
    for (int off = 128; off > 0; off >>= 1) {
        if (t < off) sd[t] += sd[t + off];
        __syncthreads();
    }
    if (t == 0) bsum[blockIdx.x] = sd[0];
}

__global__ void scan_bsums(int* __restrict__ bsum, int* __restrict__ rowptr) {
    __shared__ int sd[128];
    int t = threadIdx.x;
    int orig = (t < SCAN_BLOCKS) ? bsum[t] : 0;
    sd[t] = orig;
    __syncthreads();
    for (int off = 1; off < 128; off <<= 1) {
        int x = (t >= off) ? sd[t - off] : 0;
        __syncthreads();
        sd[t] += x;
        __syncthreads();
    }
    if (t < SCAN_BLOCKS) bsum[t] = sd[t] - orig;   // exclusive
    if (t == 0) rowptr[N_NODES] = N_EDGES;
}

__global__ void scan_apply(const int* __restrict__ deg, const int* __restrict__ bexcl,
                           int* __restrict__ rowptr, int* __restrict__ cursor) {
    __shared__ int sd[256];
    int base = blockIdx.x * SCAN_ELEMS;
    int t = threadIdx.x;
    int v[4]; int s = 0;
    #pragma unroll
    for (int j = 0; j < 4; ++j) {
        int idx = base + t * 4 + j;
        v[j] = (idx < N_NODES) ? deg[idx] : 0;
        s += v[j];
    }
    sd[t] = s;
    __syncthreads();
    for (int off = 1; off < 256; off <<= 1) {
        int x = (t >= off) ? sd[t - off] : 0;
        __syncthreads();
        sd[t] += x;
        __syncthreads();
    }
    int run = bexcl[blockIdx.x] + (sd[t] - s);
    #pragma unroll
    for (int j = 0; j < 4; ++j) {
        int idx = base + t * 4 + j;
        if (idx < N_NODES) { rowptr[idx] = run; cursor[idx] = run; }
        run += v[j];
    }
}

__global__ void scatter_csr(const int* __restrict__ src, const int* __restrict__ dst,
                            int* __restrict__ cursor, int* __restrict__ csr) {
    int i = blockIdx.x * blockDim.x + threadIdx.x;
    int stride = gridDim.x * blockDim.x;
    for (; i < N_EDGES; i += stride) {
        int d = dst[i];
        int pos = atomicAdd(&cursor[d], 1);
        csr[pos] = src[i];
    }
}

// ---------------- weight transpose/convert ----------------
// W [K][N] fp32 -> BT [Npad][K] bf16 (zero pad rows n>=N)
__global__ void transpose_w(const float* __restrict__ W, ushort* __restrict__ BT,
                            int K, int N, int Npad) {
    int i = blockIdx.x * blockDim.x + threadIdx.x;
    if (i >= Npad * K) return;
    int n = i / K, k = i - n * K;
    float v = (n < N) ? W[(size_t)k * N + n] : 0.f;
    BT[i] = f2bf(v);
}

// ---------------- MFMA GEMM layer1: fp32 X (K=256), fused bf16 convert ----------------

__global__ __launch_bounds__(256) void mfma_gemm1(const float* __restrict__ X,
                                                  const ushort* __restrict__ BT,
                                                  ushort* __restrict__ Y) {
    __shared__ ushort As_[64][40];
    __shared__ ushort Bs[128][40];
    int m0 = blockIdx.x * 64;
    int t = threadIdx.x;
    int wave = t >> 6, lane = t & 63;
    int wm = wave >> 1, wn = wave & 1;
    f32x4 acc[2][4] = {};
    for (int kt = 0; kt < 256; kt += 32) {
        {
            int r = t >> 2, kg = (t & 3) << 3;
            int rr = (m0 + r < N_NODES) ? m0 + r : N_NODES - 1;   // clamp: avoid OOB read of d_in
            float4 xa = *(const float4*)&X[(size_t)rr * 256 + kt + kg];
            float4 xb = *(const float4*)&X[(size_t)rr * 256 + kt + kg + 4];
            ushort o[8] = { f2bf(xa.x), f2bf(xa.y), f2bf(xa.z), f2bf(xa.w),
                            f2bf(xb.x), f2bf(xb.y), f2bf(xb.z), f2bf(xb.w) };
            *(s16x8*)&As_[r][kg] = *(s16x8*)o;
        }
        #pragma unroll
        for (int i = 0; i < 2; ++i) {
            int idx = t + (i << 8);
            int r = idx >> 2, kg = (idx & 3) << 3;
            *(s16x8*)&Bs[r][kg] = *(const s16x8*)&BT[(size_t)r * 256 + kt + kg];
        }
        __syncthreads();
        int row = lane & 15, koff = (lane >> 4) << 3;
        s16x8 a[2], b[4];
        #pragma unroll
        for (int mf = 0; mf < 2; ++mf)
            a[mf] = *(s16x8*)&As_[wm * 32 + mf * 16 + row][koff];
        #pragma unroll
        for (int nf = 0; nf < 4; ++nf)
            b[nf] = *(s16x8*)&Bs[wn * 64 + nf * 16 + row][koff];
        #pragma unroll
        for (int mf = 0; mf < 2; ++mf)
            #pragma unroll
            for (int nf = 0; nf < 4; ++nf)
                acc[mf][nf] = __builtin_amdgcn_mfma_f32_16x16x32_bf16(a[mf], b[nf], acc[mf][nf], 0, 0, 0);
        __syncthreads();
    }
    int colb = lane & 15, rowb = (lane >> 4) << 2;
    #pragma unroll
    for (int mf = 0; mf < 2; ++mf)
        #pragma unroll
        for (int nf = 0; nf < 4; ++nf)
            #pragma unroll
            for (int reg = 0; reg < 4; ++reg) {
                int row = m0 + wm * 32 + mf * 16 + rowb + reg;
                int col = wn * 64 + nf * 16 + colb;
                if (row < N_NODES) Y[(size_t)row * 128 + col] = f2bf(acc[mf][nf][reg]);
            }
}

// ---------------- MFMA GEMM, bf16 in, N=128 out bf16 (layer 2) ----------------

template <int K>
__global__ __launch_bounds__(256) void mfma_gemm_nc128(const ushort* __restrict__ X,
                                                       const ushort* __restrict__ BT,
                                                       ushort* __restrict__ Y) {
    __shared__ ushort As_[64][40];
    __shared__ ushort Bs[128][40];
    int m0 = blockIdx.x * 64;
    int t = threadIdx.x;
    int wave = t >> 6, lane = t & 63;
    int wm = wave >> 1, wn = wave & 1;
    f32x4 acc[2][4] = {};
    for (int kt = 0; kt < K; kt += 32) {
        {
            int r = t >> 2, kg = (t & 3) << 3;
            *(s16x8*)&As_[r][kg] = *(const s16x8*)&X[(size_t)(m0 + r) * K + kt + kg];
        }
        #pragma unroll
        for (int i = 0; i < 2; ++i) {
            int idx = t + (i << 8);
            int r = idx >> 2, kg = (idx & 3) << 3;
            *(s16x8*)&Bs[r][kg] = *(const s16x8*)&BT[(size_t)r * K + kt + kg];
        }
        __syncthreads();
        int row = lane & 15, koff = (lane >> 4) << 3;
        s16x8 a[2], b[4];
        #pragma unroll
        for (int mf = 0; mf < 2; ++mf)
            a[mf] = *(s16x8*)&As_[wm * 32 + mf * 16 + row][koff];
        #pragma unroll
        for (int nf = 0; nf < 4; ++nf)
            b[nf] = *(s16x8*)&Bs[wn * 64 + nf * 16 + row][koff];
        #pragma unroll
        for (int mf = 0; mf < 2; ++mf)
            #pragma unroll
            for (int nf = 0; nf < 4; ++nf)
                acc[mf][nf] = __builtin_amdgcn_mfma_f32_16x16x32_bf16(a[mf], b[nf], acc[mf][nf], 0, 0, 0);
        __syncthreads();
    }
    int colb = lane & 15, rowb = (lane >> 4) << 2;
    #pragma unroll
    for (int mf = 0; mf < 2; ++mf)
        #pragma unroll
        for (int nf = 0; nf < 4; ++nf)
            #pragma unroll
            for (int reg = 0; reg < 4; ++reg) {
                int row = m0 + wm * 32 + mf * 16 + rowb + reg;
                int col = wn * 64 + nf * 16 + colb;
                if (row < N_NODES) Y[(size_t)row * 128 + col] = f2bf(acc[mf][nf][reg]);
            }
}

// ---------------- MFMA GEMM, K=128, N=40 (padded 48), out fp32 ----------------

__global__ __launch_bounds__(256) void mfma_gemm_nc40(const ushort* __restrict__ X,
                                                      const ushort* __restrict__ BT,
                                                      float* __restrict__ Y) {
    __shared__ ushort As_[64][40];
    __shared__ ushort Bs[48][40];
    int m0 = blockIdx.x * 64;
    int t = threadIdx.x, wave = t >> 6, lane = t & 63;
    f32x4 acc[3] = {};
    for (int kt = 0; kt < 128; kt += 32) {
        {
            int r = t >> 2, kg = (t & 3) << 3;
            *(s16x8*)&As_[r][kg] = *(const s16x8*)&X[(size_t)(m0 + r) * 128 + kt + kg];
        }
        if (t < 192) {
            int r = t >> 2, kg = (t & 3) << 3;
            *(s16x8*)&Bs[r][kg] = *(const s16x8*)&BT[(size_t)r * 128 + kt + kg];
        }
        __syncthreads();
        int row = lane & 15, koff = (lane >> 4) << 3;
        s16x8 a = *(s16x8*)&As_[wave * 16 + row][koff];
        #pragma unroll
        for (int nf = 0; nf < 3; ++nf) {
            s16x8 b = *(s16x8*)&Bs[nf * 16 + row][koff];
            acc[nf] = __builtin_amdgcn_mfma_f32_16x16x32_bf16(a, b, acc[nf], 0, 0, 0);
        }
        __syncthreads();
    }
    int colb = lane & 15, rowb = (lane >> 4) << 2;
    #pragma unroll
    for (int nf = 0; nf < 3; ++nf)
        #pragma unroll
        for (int reg = 0; reg < 4; ++reg) {
            int row = m0 + wave * 16 + rowb + reg;
            int col = nf * 16 + colb;
            if (row < N_NODES && col < 40) Y[(size_t)row * 40 + col] = acc[nf][reg];
        }
}

// ---------------- attention coefficients ----------------

template <int WD, int NH, int SEG>
__global__ void as_ad_bf16(const ushort* __restrict__ XH, const float* __restrict__ asrc,
                           const float* __restrict__ adst, float* __restrict__ As,
                           float* __restrict__ Ad) {
    int node = (int)((blockIdx.x * blockDim.x + threadIdx.x) >> 6);
    int lane = threadIdx.x & 63;
    if (node >= N_NODES) return;
    int c0 = lane * 2;
    uint xv = *reinterpret_cast<const uint*>(&XH[(size_t)node * WD + c0]);
    float x0 = bf2f((ushort)(xv & 0xFFFF)), x1 = bf2f((ushort)(xv >> 16));
    float2 a = *reinterpret_cast<const float2*>(&asrc[c0]);
    float2 b = *reinterpret_cast<const float2*>(&adst[c0]);
    float s = x0 * a.x + x1 * a.y;
    float d = x0 * b.x + x1 * b.y;
    #pragma unroll
    for (int off = 1; off < SEG; off <<= 1) {
        s += __shfl_xor(s, off, 64);
        d += __shfl_xor(d, off, 64);
    }
    if ((lane % SEG) == 0) {
        int h = c0 / (WD / NH);
        As[(size_t)node * NH + h] = s;
        Ad[(size_t)node * NH + h] = d;
    }
}

template <int WD, int NH, int SEG>
__global__ void as_ad_f32(const float* __restrict__ XH, const float* __restrict__ asrc,
                          const float* __restrict__ adst, float* __restrict__ As,
                          float* __restrict__ Ad) {
    int node = (int)((blockIdx.x * blockDim.x + threadIdx.x) >> 6);
    int lane = threadIdx.x & 63;
    if (node >= N_NODES) return;
    int c0 = lane * 2;
    float s = 0.f, d = 0.f;
    if (c0 < WD) {
        float2 x = *reinterpret_cast<const float2*>(&XH[(size_t)node * WD + c0]);
        float2 a = *reinterpret_cast<const float2*>(&asrc[c0]);
        float2 b = *reinterpret_cast<const float2*>(&adst[c0]);
        s = x.x * a.x + x.y * a.y;
        d = x.x * b.x + x.y * b.y;
    }
    #pragma unroll
    for (int off = 1; off < SEG; off <<= 1) {
        s += __shfl_xor(s, off, 64);
        d += __shfl_xor(d, off, 64);
    }
    if ((lane % SEG) == 0 && c0 < WD) {
        int h = c0 / (WD / NH);
        As[(size_t)node * NH + h] = s;
        Ad[(size_t)node * NH + h] = d;
    }
}

// ---------------- softmax scalars: per-node max/denominator -> per-edge alpha ----------------
// wave per node, lanes parallel over incoming edges (+ implicit self at index deg).

__global__ void softmax_md1(const float* __restrict__ As, const float* __restrict__ Ad,
                            const int* __restrict__ rowptr, const int* __restrict__ csr,
                            float* __restrict__ aE, float* __restrict__ aS) {
    int node = (int)((blockIdx.x * blockDim.x + threadIdx.x) >> 6);
    int lane = threadIdx.x & 63;
    if (node >= N_NODES) return;
    int beg = rowptr[node], deg = rowptr[node + 1] - beg;
    float adi = Ad[node];
    float m = -1e30f;
    for (int i = lane; i <= deg; i += 64) {
        int src = (i < deg) ? csr[beg + i] : node;
        m = fmaxf(m, lrelu(As[src] + adi));
    }
    #pragma unroll
    for (int off = 1; off < 64; off <<= 1) m = fmaxf(m, __shfl_xor(m, off, 64));
    float den = 0.f;
    for (int i = lane; i <= deg; i += 64) {
        int src = (i < deg) ? csr[beg + i] : node;
        den += __expf(lrelu(As[src] + adi) - m);
    }
    #pragma unroll
    for (int off = 1; off < 64; off <<= 1) den += __shfl_xor(den, off, 64);
    float dinv = 1.0f / den;
    for (int i = lane; i <= deg; i += 64) {
        int src = (i < deg) ? csr[beg + i] : node;
        float a = __expf(lrelu(As[src] + adi) - m) * dinv;
        if (i < deg) aE[beg + i] = a; else aS[node] = a;
    }
}

__global__ void softmax_md4(const float* __restrict__ As, const float* __restrict__ Ad,
                            const int* __restrict__ rowptr, const int* __restrict__ csr,
                            float* __restrict__ aE, float* __restrict__ aS) {
    int node = (int)((blockIdx.x * blockDim.x + threadIdx.x) >> 6);
    int lane = threadIdx.x & 63;
    if (node >= N_NODES) return;
    int h = lane & 3, il = lane >> 2;
    int beg = rowptr[node], deg = rowptr[node + 1] - beg;
    float adi = Ad[(size_t)node * 4 + h];
    float m = -1e30f;
    for (int i = il; i <= deg; i += 16) {
        int src = (i < deg) ? csr[beg + i] : node;
        m = fmaxf(m, lrelu(As[(size_t)src * 4 + h] + adi));
    }
    #pragma unroll
    for (int off = 4; off < 64; off <<= 1) m = fmaxf(m, __shfl_xor(m, off, 64));
    float den = 0.f;
    for (int i = il; i <= deg; i += 16) {
        int src = (i < deg) ? csr[beg + i] : node;
        den += __expf(lrelu(As[(size_t)src * 4 + h] + adi) - m);
    }
    #pragma unroll
    for (int off = 4; off < 64; off <<= 1) den += __shfl_xor(den, off, 64);
    float dinv = 1.0f / den;
    for (int i = il; i <= deg; i += 16) {
        int src = (i < deg) ? csr[beg + i] : node;
        float a = __expf(lrelu(As[(size_t)src * 4 + h] + adi) - m) * dinv;
        if (i < deg) aE[(size_t)(beg + i) * 4 + h] = a;
        else aS[(size_t)node * 4 + h] = a;
    }
}

// ---------------- aggregation: precomputed-alpha weighted gather ----------------
// WD=128 bf16: wave per node, lane owns cols 2l,2l+1; 4 row-gathers in flight.

template <int NH>
__global__ void aggregate3_bf16(const ushort* __restrict__ XH, const float* __restrict__ aE,
                                const float* __restrict__ aS, const float* __restrict__ bias,
                                const int* __restrict__ rowptr, const int* __restrict__ csr,
                                ushort* __restrict__ Y) {
    int node = (int)((blockIdx.x * blockDim.x + threadIdx.x) >> 6);
    int lane = threadIdx.x & 63;
    if (node >= N_NODES) return;
    int c0 = lane * 2;
    int h = (NH == 4) ? (lane >> 4) : 0;     // c0/32
    int beg = rowptr[node], deg = rowptr[node + 1] - beg;
    float acc0, acc1;
    {
        float a = aS[(size_t)node * NH + h];
        uint rv = *(const uint*)&XH[(size_t)node * 128 + c0];
        acc0 = a * bf2f((ushort)(rv & 0xFFFF));
        acc1 = a * bf2f((ushort)(rv >> 16));
    }
    int j = 0;
    for (; j + 4 <= deg; j += 4) {
        int b = beg + j;
        int s0 = csr[b], s1 = csr[b + 1], s2 = csr[b + 2], s3 = csr[b + 3];
        float a0 = aE[(size_t)(b + 0) * NH + h];
        float a1 = aE[(size_t)(b + 1) * NH + h];
        float a2 = aE[(size_t)(b + 2) * NH + h];
        float a3 = aE[(size_t)(b + 3) * NH + h];
        uint r0 = *(const uint*)&XH[(size_t)s0 * 128 + c0];
        uint r1 = *(const uint*)&XH[(size_t)s1 * 128 + c0];
        uint r2 = *(const uint*)&XH[(size_t)s2 * 128 + c0];
        uint r3 = *(const uint*)&XH[(size_t)s3 * 128 + c0];
        acc0 += a0 * bf2f((ushort)(r0 & 0xFFFF)); acc1 += a0 * bf2f((ushort)(r0 >> 16));
        acc0 += a1 * bf2f((ushort)(r1 & 0xFFFF)); acc1 += a1 * bf2f((ushort)(r1 >> 16));
        acc0 += a2 * bf2f((ushort)(r2 & 0xFFFF)); acc1 += a2 * bf2f((ushort)(r2 >> 16));
        acc0 += a3 * bf2f((ushort)(r3 & 0xFFFF)); acc1 += a3 * bf2f((ushort)(r3 >> 16));
    }
    for (; j < deg; ++j) {
        int b = beg + j;
        int s = csr[b];
        float a = aE[(size_t)b * NH + h];
        uint rv = *(const uint*)&XH[(size_t)s * 128 + c0];
        acc0 += a * bf2f((ushort)(rv & 0xFFFF));
        acc1 += a * bf2f((ushort)(rv >> 16));
    }
    float o0 = fmaxf(acc0 + bias[c0], 0.f);
    float o1 = fmaxf(acc1 + bias[c0 + 1], 0.f);
    uint packed = (uint)f2bf(o0) | ((uint)f2bf(o1) << 16);
    *reinterpret_cast<uint*>(&Y[(size_t)node * 128 + c0]) = packed;
}

// WD=40 fp32 (layer 3): 12 nodes per 256-thread block, 20 lanes/node.

__global__ __launch_bounds__(256) void aggregate3_f32_40(const float* __restrict__ XH,
                                                         const float* __restrict__ aE,
                                                         const float* __restrict__ aS,
                                                         const float* __restrict__ bias,
                                                         const int* __restrict__ rowptr,
                                                         const int* __restrict__ csr,
                                                         float* __restrict__ Y) {
    int t = threadIdx.x;
    int sub = t / 20, cp = t % 20;
    int node = blockIdx.x * 12 + sub;
    if (sub >= 12 || node >= N_NODES) return;
    int c0 = cp * 2;
    int beg = rowptr[node], deg = rowptr[node + 1] - beg;
    float acc0, acc1;
    {
        float a = aS[node];
        float2 x = *(const float2*)&XH[(size_t)node * 40 + c0];
        acc0 = a * x.x; acc1 = a * x.y;
    }
    int j = 0;
    for (; j + 4 <= deg; j += 4) {
        int b = beg + j;
        int s0 = csr[b], s1 = csr[b + 1], s2 = csr[b + 2], s3 = csr[b + 3];
        float a0 = aE[b], a1 = aE[b + 1], a2 = aE[b + 2], a3 = aE[b + 3];
        float2 r0 = *(const float2*)&XH[(size_t)s0 * 40 + c0];
        float2 r1 = *(const float2*)&XH[(size_t)s1 * 40 + c0];
        float2 r2 = *(const float2*)&XH[(size_t)s2 * 40 + c0];
        float2 r3 = *(const float2*)&XH[(size_t)s3 * 40 + c0];
        acc0 += a0 * r0.x; acc1 += a0 * r0.y;
        acc0 += a1 * r1.x; acc1 += a1 * r1.y;
        acc0 += a2 * r2.x; acc1 += a2 * r2.y;
        acc0 += a3 * r3.x; acc1 += a3 * r3.y;
    }
    for (; j < deg; ++j) {
        int b = beg + j;
        int s = csr[b];
        float a = aE[b];
        float2 rv = *(const float2*)&XH[(size_t)s * 40 + c0];
        acc0 += a * rv.x; acc1 += a * rv.y;
    }
    acc0 += bias[c0]; acc1 += bias[c0 + 1];
    *reinterpret_cast<float2*>(&Y[(size_t)node * 40 + c0]) = make_float2(acc0, acc1);
}

// ---------------- log-softmax over 40 classes ----------------

__global__ void logsoftmax_kernel(float* __restrict__ Y) {
    int node = (int)((blockIdx.x * blockDim.x + threadIdx.x) >> 6);
    int lane = threadIdx.x & 63;
    if (node >= N_NODES) return;
    float v = (lane < 40) ? Y[(size_t)node * 40 + lane] : -1e30f;
    float mm = v;
    #pragma unroll
    for (int off = 1; off < 64; off <<= 1) mm = fmaxf(mm, __shfl_xor(mm, off, 64));
    float p = (lane < 40) ? __expf(v - mm) : 0.f;
    #pragma unroll
    for (int off = 1; off < 64; off <<= 1) p += __shfl_xor(p, off, 64);
    float r = v - mm - __logf(p);
    if (lane < 40) Y[(size_t)node * 40 + lane] = r;
}

// ---------------- launch ----------------

static inline size_t align256(size_t x) { return (x + 255) & ~(size_t)255; }

extern "C" void kernel_launch(void* const* d_in, const int* in_sizes, int n_in,
                              void* d_out, int out_size, void* d_ws, size_t ws_size,
                              hipStream_t stream) {
    const int*   edge = (const int*)d_in[0];
    const float* feat = (const float*)d_in[1];
    const float* W1   = (const float*)d_in[2];
    const float* as1  = (const float*)d_in[3];
    const float* ad1  = (const float*)d_in[4];
    const float* b1   = (const float*)d_in[5];
    const float* W2   = (const float*)d_in[6];
    const float* as2  = (const float*)d_in[7];
    const float* ad2  = (const float*)d_in[8];
    const float* b2   = (const float*)d_in[9];
    const float* W3   = (const float*)d_in[10];
    const float* as3  = (const float*)d_in[11];
    const float* ad3  = (const float*)d_in[12];
    const float* b3   = (const float*)d_in[13];
    float* out = (float*)d_out;

    const int* srcArr = edge;
    const int* dstArr = edge + N_EDGES;

    const size_t NB128 = (size_t)N_NODES * 128 * 2;   // 25.6 MB

    char* w = (char*)d_ws;
    char* regionA = w; w += align256(2 * NB128);      // layer1 alpha (aliased), later xh2|h2
    char* regionB = w; w += align256(NB128);          // xh1; later xh3 fp32 (16MB)
    char* regionC = w; w += align256(NB128);          // h1
    float* As   = (float*)w; w += align256((size_t)N_NODES * 4 * 4);
    float* Ad   = (float*)w; w += align256((size_t)N_NODES * 4 * 4);
    int* rowptr = (int*)w;   w += align256((size_t)(N_NODES + 1) * 4);
    int* cursor = (int*)w;   w += align256((size_t)N_NODES * 4);
    int* deg    = (int*)w;   w += align256((size_t)N_NODES * 4);
    int* bsum   = (int*)w;   w += align256((size_t)256 * 4);
    int* csr    = (int*)w;   w += align256((size_t)N_EDGES * 4);
    ushort* WT1 = (ushort*)w; w += align256((size_t)128 * 256 * 2);
    ushort* WT2 = (ushort*)w; w += align256((size_t)128 * 128 * 2);
    ushort* WT3 = (ushort*)w; w += align256((size_t)48 * 128 * 2);
    float* aEs  = (float*)w; w += align256((size_t)N_EDGES * 4);      // NH=1 edge alpha
    float* aSs  = (float*)w; w += align256((size_t)N_NODES * 4);      // NH=1 self alpha

    ushort* xh1 = (ushort*)regionB;                   // [100k][128] bf16
    ushort* h1  = (ushort*)regionC;                   // [100k][128] bf16
    float*  a1E = (float*)regionA;                    // [E][4] alpha (layer1), dead before xh2
    float*  a1S = (float*)(regionA + NB128);          // [N][4]
    ushort* xh2 = (ushort*)regionA;                   // [100k][128] bf16 (after layer1 agg)
    ushort* h2  = (ushort*)(regionA + NB128);         // [100k][128] bf16
    float*  xh3 = (float*)regionB;                    // [100k][40] fp32 (after layer2 agg... xh1 dead)

    // CSR
    hipMemsetAsync(deg, 0, (size_t)N_NODES * 4, stream);
    hist_kernel<<<512, 256, 0, stream>>>(dstArr, deg);
    scan_reduce<<<SCAN_BLOCKS, 256, 0, stream>>>(deg, bsum);
    scan_bsums<<<1, 128, 0, stream>>>(bsum, rowptr);
    scan_apply<<<SCAN_BLOCKS, 256, 0, stream>>>(deg, bsum, rowptr, cursor);
    scatter_csr<<<512, 256, 0, stream>>>(srcArr, dstArr, cursor, csr);

    // weights
    transpose_w<<<(128 * 256 + 255) / 256, 256, 0, stream>>>(W1, WT1, 256, 128, 128);
    transpose_w<<<(128 * 128 + 255) / 256, 256, 0, stream>>>(W2, WT2, 128, 128, 128);
    transpose_w<<<(48 * 128 + 255) / 256, 256, 0, stream>>>(W3, WT3, 128, 40, 48);

    int aggGrid = (N_NODES + 3) / 4;          // wave-per-node kernels
    int gemmGrid = (N_NODES + 63) / 64;

    // ---- layer 1: 256 -> 4x32, relu ----
    mfma_gemm1<<<gemmGrid, 256, 0, stream>>>(feat, WT1, xh1);
    as_ad_bf16<128, 4, 16><<<aggGrid, 256, 0, stream>>>(xh1, as1, ad1, As, Ad);
    softmax_md4<<<aggGrid, 256, 0, stream>>>(As, Ad, rowptr, csr, a1E, a1S);
    aggregate3_bf16<4><<<aggGrid, 256, 0, stream>>>(xh1, a1E, a1S, b1, rowptr, csr, h1);

    // ---- layer 2: 128 -> 128, relu ----
    mfma_gemm_nc128<128><<<gemmGrid, 256, 0, stream>>>(h1, WT2, xh2);
    as_ad_bf16<128, 1, 64><<<aggGrid, 256, 0, stream>>>(xh2, as2, ad2, As, Ad);
    softmax_md1<<<aggGrid, 256, 0, stream>>>(As, Ad, rowptr, csr, aEs, aSs);
    aggregate3_bf16<1><<<aggGrid, 256, 0, stream>>>(xh2, aEs, aSs, b2, rowptr, csr, h2);

    // ---- layer 3: 128 -> 40 ----
    mfma_gemm_nc40<<<gemmGrid, 256, 0, stream>>>(h2, WT3, xh3);
    as_ad_f32<40, 1, 64><<<aggGrid, 256, 0, stream>>>(xh3, as3, ad3, As, Ad);
    softmax_md1<<<aggGrid, 256, 0, stream>>>(As, Ad, rowptr, csr, aEs, aSs);
    aggregate3_f32_40<<<(N_NODES + 11) / 12, 256, 0, stream>>>(xh3, aEs, aSs, b3, rowptr, csr, out);
    logsoftmax_kernel<<<aggGrid, 256, 0, stream>>>(out);
}

// Round 7
// 532.119 us; speedup vs baseline: 1.9090x; 1.2406x over previous
//
#include <hip/hip_runtime.h>
#include <cstdint>

#define N_NODES 100000
#define N_EDGES 1600000
#define NEG_SLOPE 0.2f

#define NBUCK 391          // ceil(100000/256), bucket = dst >> 8
#define NCHUNK 128
#define CHUNK_SZ ((N_EDGES + NCHUNK - 1) / NCHUNK)   // 12500

typedef short s16x8 __attribute__((ext_vector_type(8)));
typedef float f32x4 __attribute__((ext_vector_type(4)));

__device__ inline float bf2f(ushort u) {
    union { uint i; float f; } x; x.i = ((uint)u) << 16; return x.f;
}
__device__ inline ushort f2bf(float f) {
    union { float f; uint i; } x; x.f = f;
    uint r = x.i + 0x7FFF + ((x.i >> 16) & 1);   // RNE
    return (ushort)(r >> 16);
}
__device__ inline float lrelu(float e) { return (e > 0.f) ? e : NEG_SLOPE * e; }

// ---------------- CSR build: 2-level bucket counting sort ----------------

// Phase 1: per-chunk histogram over 391 buckets (LDS only).
__global__ __launch_bounds__(256) void bucket_hist(const int* __restrict__ dst,
                                                   int* __restrict__ chunkCnt) {
    __shared__ int cnt[NBUCK];
    int t = threadIdx.x, blk = blockIdx.x;
    for (int b = t; b < NBUCK; b += 256) cnt[b] = 0;
    __syncthreads();
    int beg = blk * CHUNK_SZ, end = min(beg + CHUNK_SZ, N_EDGES);
    for (int i = beg + t; i < end; i += 256) atomicAdd(&cnt[dst[i] >> 8], 1);
    __syncthreads();
    for (int b = t; b < NBUCK; b += 256) chunkCnt[blk * NBUCK + b] = cnt[b];
}

// Phase 2: scan. chunkBase[c][b] = offset of chunk c within bucket b;
// bucketBase[b] = global start of bucket b. Single block, 512 threads.
__global__ __launch_bounds__(512) void bucket_scan(const int* __restrict__ chunkCnt,
                                                   int* __restrict__ chunkBase,
                                                   int* __restrict__ bucketBase) {
    __shared__ int tot[512];
    int b = threadIdx.x;
    int run = 0;
    if (b < NBUCK) {
        for (int c = 0; c < NCHUNK; ++c) {
            chunkBase[c * NBUCK + b] = run;
            run += chunkCnt[c * NBUCK + b];
        }
    }
    tot[b] = (b < NBUCK) ? run : 0;
    __syncthreads();
    for (int off = 1; off < 512; off <<= 1) {
        int x = (b >= off) ? tot[b - off] : 0;
        __syncthreads();
        tot[b] += x;
        __syncthreads();
    }
    if (b == 0) bucketBase[0] = 0;
    if (b < NBUCK) bucketBase[b + 1] = tot[b];   // inclusive -> base of b+1
}

// Phase 3: scatter (src,dst) pairs into bucket-partitioned regions.
__global__ __launch_bounds__(256) void bucket_scatter(const int* __restrict__ src,
                                                      const int* __restrict__ dst,
                                                      const int* __restrict__ chunkBase,
                                                      const int* __restrict__ bucketBase,
                                                      int2* __restrict__ pairs) {
    __shared__ int cur[NBUCK];
    int t = threadIdx.x, blk = blockIdx.x;
    for (int b = t; b < NBUCK; b += 256)
        cur[b] = bucketBase[b] + chunkBase[blk * NBUCK + b];
    __syncthreads();
    int beg = blk * CHUNK_SZ, end = min(beg + CHUNK_SZ, N_EDGES);
    for (int i = beg + t; i < end; i += 256) {
        int d = dst[i];
        int pos = atomicAdd(&cur[d >> 8], 1);
        pairs[pos] = make_int2(src[i], d);
    }
}

// Phase 4: per-bucket local counting sort -> rowptr + csr.
__global__ __launch_bounds__(256) void bucket_build(const int2* __restrict__ pairs,
                                                    const int* __restrict__ bucketBase,
                                                    int* __restrict__ rowptr,
                                                    int* __restrict__ csr) {
    __shared__ int cnt[256], pre[256];
    int b = blockIdx.x, t = threadIdx.x;
    cnt[t] = 0;
    __syncthreads();
    int beg = bucketBase[b], end = bucketBase[b + 1];
    for (int i = beg + t; i < end; i += 256) atomicAdd(&cnt[pairs[i].y & 255], 1);
    __syncthreads();
    int v = cnt[t];
    pre[t] = v;
    __syncthreads();
    for (int off = 1; off < 256; off <<= 1) {
        int x = (t >= off) ? pre[t - off] : 0;
        __syncthreads();
        pre[t] += x;
        __syncthreads();
    }
    int excl = pre[t] - v;
    int node = b * 256 + t;
    if (node <= N_NODES) rowptr[node] = beg + excl;
    cnt[t] = excl;   // reuse as cursor
    __syncthreads();
    for (int i = beg + t; i < end; i += 256) {
        int2 p = pairs[i];
        int pos = beg + atomicAdd(&cnt[p.y & 255], 1);
        csr[pos] = p.x;
    }
}

// ---------------- weight transpose/convert ----------------
// W [K][N] fp32 -> BT [Npad][K] bf16 (zero pad rows n>=N)
__global__ void transpose_w(const float* __restrict__ W, ushort* __restrict__ BT,
                            int K, int N, int Npad) {
    int i = blockIdx.x * blockDim.x + threadIdx.x;
    if (i >= Npad * K) return;
    int n = i / K, k = i - n * K;
    float v = (n < N) ? W[(size_t)k * N + n] : 0.f;
    BT[i] = f2bf(v);
}

// ---------------- MFMA GEMM layer1: fp32 X (K=256), fused bf16 convert ----------------

__global__ __launch_bounds__(256) void mfma_gemm1(const float* __restrict__ X,
                                                  const ushort* __restrict__ BT,
                                                  ushort* __restrict__ Y) {
    __shared__ ushort As_[64][40];
    __shared__ ushort Bs[128][40];
    int m0 = blockIdx.x * 64;
    int t = threadIdx.x;
    int wave = t >> 6, lane = t & 63;
    int wm = wave >> 1, wn = wave & 1;
    f32x4 acc[2][4] = {};
    for (int kt = 0; kt < 256; kt += 32) {
        {
            int r = t >> 2, kg = (t & 3) << 3;
            int rr = (m0 + r < N_NODES) ? m0 + r : N_NODES - 1;   // clamp: avoid OOB read of d_in
            float4 xa = *(const float4*)&X[(size_t)rr * 256 + kt + kg];
            float4 xb = *(const float4*)&X[(size_t)rr * 256 + kt + kg + 4];
            ushort o[8] = { f2bf(xa.x), f2bf(xa.y), f2bf(xa.z), f2bf(xa.w),
                            f2bf(xb.x), f2bf(xb.y), f2bf(xb.z), f2bf(xb.w) };
            *(s16x8*)&As_[r][kg] = *(s16x8*)o;
        }
        #pragma unroll
        for (int i = 0; i < 2; ++i) {
            int idx = t + (i << 8);
            int r = idx >> 2, kg = (idx & 3) << 3;
            *(s16x8*)&Bs[r][kg] = *(const s16x8*)&BT[(size_t)r * 256 + kt + kg];
        }
        __syncthreads();
        int row = lane & 15, koff = (lane >> 4) << 3;
        s16x8 a[2], b[4];
        #pragma unroll
        for (int mf = 0; mf < 2; ++mf)
            a[mf] = *(s16x8*)&As_[wm * 32 + mf * 16 + row][koff];
        #pragma unroll
        for (int nf = 0; nf < 4; ++nf)
            b[nf] = *(s16x8*)&Bs[wn * 64 + nf * 16 + row][koff];
        #pragma unroll
        for (int mf = 0; mf < 2; ++mf)
            #pragma unroll
            for (int nf = 0; nf < 4; ++nf)
                acc[mf][nf] = __builtin_amdgcn_mfma_f32_16x16x32_bf16(a[mf], b[nf], acc[mf][nf], 0, 0, 0);
        __syncthreads();
    }
    int colb = lane & 15, rowb = (lane >> 4) << 2;
    #pragma unroll
    for (int mf = 0; mf < 2; ++mf)
        #pragma unroll
        for (int nf = 0; nf < 4; ++nf)
            #pragma unroll
            for (int reg = 0; reg < 4; ++reg) {
                int row = m0 + wm * 32 + mf * 16 + rowb + reg;
                int col = wn * 64 + nf * 16 + colb;
                if (row < N_NODES) Y[(size_t)row * 128 + col] = f2bf(acc[mf][nf][reg]);
            }
}

// ---------------- MFMA GEMM, bf16 in, N=128 out bf16 (layer 2) ----------------

template <int K>
__global__ __launch_bounds__(256) void mfma_gemm_nc128(const ushort* __restrict__ X,
                                                       const ushort* __restrict__ BT,
                                                       ushort* __restrict__ Y) {
    __shared__ ushort As_[64][40];
    __shared__ ushort Bs[128][40];
    int m0 = blockIdx.x * 64;
    int t = threadIdx.x;
    int wave = t >> 6, lane = t & 63;
    int wm = wave >> 1, wn = wave & 1;
    f32x4 acc[2][4] = {};
    for (int kt = 0; kt < K; kt += 32) {
        {
            int r = t >> 2, kg = (t & 3) << 3;
            *(s16x8*)&As_[r][kg] = *(const s16x8*)&X[(size_t)(m0 + r) * K + kt + kg];
        }
        #pragma unroll
        for (int i = 0; i < 2; ++i) {
            int idx = t + (i << 8);
            int r = idx >> 2, kg = (idx & 3) << 3;
            *(s16x8*)&Bs[r][kg] = *(const s16x8*)&BT[(size_t)r * K + kt + kg];
        }
        __syncthreads();
        int row = lane & 15, koff = (lane >> 4) << 3;
        s16x8 a[2], b[4];
        #pragma unroll
        for (int mf = 0; mf < 2; ++mf)
            a[mf] = *(s16x8*)&As_[wm * 32 + mf * 16 + row][koff];
        #pragma unroll
        for (int nf = 0; nf < 4; ++nf)
            b[nf] = *(s16x8*)&Bs[wn * 64 + nf * 16 + row][koff];
        #pragma unroll
        for (int mf = 0; mf < 2; ++mf)
            #pragma unroll
            for (int nf = 0; nf < 4; ++nf)
                acc[mf][nf] = __builtin_amdgcn_mfma_f32_16x16x32_bf16(a[mf], b[nf], acc[mf][nf], 0, 0, 0);
        __syncthreads();
    }
    int colb = lane & 15, rowb = (lane >> 4) << 2;
    #pragma unroll
    for (int mf = 0; mf < 2; ++mf)
        #pragma unroll
        for (int nf = 0; nf < 4; ++nf)
            #pragma unroll
            for (int reg = 0; reg < 4; ++reg) {
                int row = m0 + wm * 32 + mf * 16 + rowb + reg;
                int col = wn * 64 + nf * 16 + colb;
                if (row < N_NODES) Y[(size_t)row * 128 + col] = f2bf(acc[mf][nf][reg]);
            }
}

// ---------------- MFMA GEMM, K=128, N=40 (padded 48), out fp32 ----------------

__global__ __launch_bounds__(256) void mfma_gemm_nc40(const ushort* __restrict__ X,
                                                      const ushort* __restrict__ BT,
                                                      float* __restrict__ Y) {
    __shared__ ushort As_[64][40];
    __shared__ ushort Bs[48][40];
    int m0 = blockIdx.x * 64;
    int t = threadIdx.x, wave = t >> 6, lane = t & 63;
    f32x4 acc[3] = {};
    for (int kt = 0; kt < 128; kt += 32) {
        {
            int r = t >> 2, kg = (t & 3) << 3;
            *(s16x8*)&As_[r][kg] = *(const s16x8*)&X[(size_t)(m0 + r) * 128 + kt + kg];
        }
        if (t < 192) {
            int r = t >> 2, kg = (t & 3) << 3;
            *(s16x8*)&Bs[r][kg] = *(const s16x8*)&BT[(size_t)r * 128 + kt + kg];
        }
        __syncthreads();
        int row = lane & 15, koff = (lane >> 4) << 3;
        s16x8 a = *(s16x8*)&As_[wave * 16 + row][koff];
        #pragma unroll
        for (int nf = 0; nf < 3; ++nf) {
            s16x8 b = *(s16x8*)&Bs[nf * 16 + row][koff];
            acc[nf] = __builtin_amdgcn_mfma_f32_16x16x32_bf16(a, b, acc[nf], 0, 0, 0);
        }
        __syncthreads();
    }
    int colb = lane & 15, rowb = (lane >> 4) << 2;
    #pragma unroll
    for (int nf = 0; nf < 3; ++nf)
        #pragma unroll
        for (int reg = 0; reg < 4; ++reg) {
            int row = m0 + wave * 16 + rowb + reg;
            int col = nf * 16 + colb;
            if (row < N_NODES && col < 40) Y[(size_t)row * 40 + col] = acc[nf][reg];
        }
}

// ---------------- attention coefficients ----------------

template <int WD, int NH, int SEG>
__global__ void as_ad_bf16(const ushort* __restrict__ XH, const float* __restrict__ asrc,
                           const float* __restrict__ adst, float* __restrict__ As,
                           float* __restrict__ Ad) {
    int node = (int)((blockIdx.x * blockDim.x + threadIdx.x) >> 6);
    int lane = threadIdx.x & 63;
    if (node >= N_NODES) return;
    int c0 = lane * 2;
    uint xv = *reinterpret_cast<const uint*>(&XH[(size_t)node * WD + c0]);
    float x0 = bf2f((ushort)(xv & 0xFFFF)), x1 = bf2f((ushort)(xv >> 16));
    float2 a = *reinterpret_cast<const float2*>(&asrc[c0]);
    float2 b = *reinterpret_cast<const float2*>(&adst[c0]);
    float s = x0 * a.x + x1 * a.y;
    float d = x0 * b.x + x1 * b.y;
    #pragma unroll
    for (int off = 1; off < SEG; off <<= 1) {
        s += __shfl_xor(s, off, 64);
        d += __shfl_xor(d, off, 64);
    }
    if ((lane % SEG) == 0) {
        int h = c0 / (WD / NH);
        As[(size_t)node * NH + h] = s;
        Ad[(size_t)node * NH + h] = d;
    }
}

template <int WD, int NH, int SEG>
__global__ void as_ad_f32(const float* __restrict__ XH, const float* __restrict__ asrc,
                          const float* __restrict__ adst, float* __restrict__ As,
                          float* __restrict__ Ad) {
    int node = (int)((blockIdx.x * blockDim.x + threadIdx.x) >> 6);
    int lane = threadIdx.x & 63;
    if (node >= N_NODES) return;
    int c0 = lane * 2;
    float s = 0.f, d = 0.f;
    if (c0 < WD) {
        float2 x = *reinterpret_cast<const float2*>(&XH[(size_t)node * WD + c0]);
        float2 a = *reinterpret_cast<const float2*>(&asrc[c0]);
        float2 b = *reinterpret_cast<const float2*>(&adst[c0]);
        s = x.x * a.x + x.y * a.y;
        d = x.x * b.x + x.y * b.y;
    }
    #pragma unroll
    for (int off = 1; off < SEG; off <<= 1) {
        s += __shfl_xor(s, off, 64);
        d += __shfl_xor(d, off, 64);
    }
    if ((lane % SEG) == 0 && c0 < WD) {
        int h = c0 / (WD / NH);
        As[(size_t)node * NH + h] = s;
        Ad[(size_t)node * NH + h] = d;
    }
}

// ---------------- softmax scalars: per-node max/denominator -> per-edge alpha ----------------

__global__ void softmax_md1(const float* __restrict__ As, const float* __restrict__ Ad,
                            const int* __restrict__ rowptr, const int* __restrict__ csr,
                            float* __restrict__ aE, float* __restrict__ aS) {
    int node = (int)((blockIdx.x * blockDim.x + threadIdx.x) >> 6);
    int lane = threadIdx.x & 63;
    if (node >= N_NODES) return;
    int beg = rowptr[node], deg = rowptr[node + 1] - beg;
    float adi = Ad[node];
    float m = -1e30f;
    for (int i = lane; i <= deg; i += 64) {
        int src = (i < deg) ? csr[beg + i] : node;
        m = fmaxf(m, lrelu(As[src] + adi));
    }
    #pragma unroll
    for (int off = 1; off < 64; off <<= 1) m = fmaxf(m, __shfl_xor(m, off, 64));
    float den = 0.f;
    for (int i = lane; i <= deg; i += 64) {
        int src = (i < deg) ? csr[beg + i] : node;
        den += __expf(lrelu(As[src] + adi) - m);
    }
    #pragma unroll
    for (int off = 1; off < 64; off <<= 1) den += __shfl_xor(den, off, 64);
    float dinv = 1.0f / den;
    for (int i = lane; i <= deg; i += 64) {
        int src = (i < deg) ? csr[beg + i] : node;
        float a = __expf(lrelu(As[src] + adi) - m) * dinv;
        if (i < deg) aE[beg + i] = a; else aS[node] = a;
    }
}

__global__ void softmax_md4(const float* __restrict__ As, const float* __restrict__ Ad,
                            const int* __restrict__ rowptr, const int* __restrict__ csr,
                            float* __restrict__ aE, float* __restrict__ aS) {
    int node = (int)((blockIdx.x * blockDim.x + threadIdx.x) >> 6);
    int lane = threadIdx.x & 63;
    if (node >= N_NODES) return;
    int h = lane & 3, il = lane >> 2;
    int beg = rowptr[node], deg = rowptr[node + 1] - beg;
    float adi = Ad[(size_t)node * 4 + h];
    float m = -1e30f;
    for (int i = il; i <= deg; i += 16) {
        int src = (i < deg) ? csr[beg + i] : node;
        m = fmaxf(m, lrelu(As[(size_t)src * 4 + h] + adi));
    }
    #pragma unroll
    for (int off = 4; off < 64; off <<= 1) m = fmaxf(m, __shfl_xor(m, off, 64));
    float den = 0.f;
    for (int i = il; i <= deg; i += 16) {
        int src = (i < deg) ? csr[beg + i] : node;
        den += __expf(lrelu(As[(size_t)src * 4 + h] + adi) - m);
    }
    #pragma unroll
    for (int off = 4; off < 64; off <<= 1) den += __shfl_xor(den, off, 64);
    float dinv = 1.0f / den;
    for (int i = il; i <= deg; i += 16) {
        int src = (i < deg) ? csr[beg + i] : node;
        float a = __expf(lrelu(As[(size_t)src * 4 + h] + adi) - m) * dinv;
        if (i < deg) aE[(size_t)(beg + i) * 4 + h] = a;
        else aS[(size_t)node * 4 + h] = a;
    }
}

// ---------------- aggregation: precomputed-alpha weighted gather ----------------

template <int NH>
__global__ void aggregate3_bf16(const ushort* __restrict__ XH, const float* __restrict__ aE,
                                const float* __restrict__ aS, const float* __restrict__ bias,
                                const int* __restrict__ rowptr, const int* __restrict__ csr,
                                ushort* __restrict__ Y) {
    int node = (int)((blockIdx.x * blockDim.x + threadIdx.x) >> 6);
    int lane = threadIdx.x & 63;
    if (node >= N_NODES) return;
    int c0 = lane * 2;
    int h = (NH == 4) ? (lane >> 4) : 0;     // c0/32
    int beg = rowptr[node], deg = rowptr[node + 1] - beg;
    float acc0, acc1;
    {
        float a = aS[(size_t)node * NH + h];
        uint rv = *(const uint*)&XH[(size_t)node * 128 + c0];
        acc0 = a * bf2f((ushort)(rv & 0xFFFF));
        acc1 = a * bf2f((ushort)(rv >> 16));
    }
    int j = 0;
    for (; j + 4 <= deg; j += 4) {
        int b = beg + j;
        int s0 = csr[b], s1 = csr[b + 1], s2 = csr[b + 2], s3 = csr[b + 3];
        float a0 = aE[(size_t)(b + 0) * NH + h];
        float a1 = aE[(size_t)(b + 1) * NH + h];
        float a2 = aE[(size_t)(b + 2) * NH + h];
        float a3 = aE[(size_t)(b + 3) * NH + h];
        uint r0 = *(const uint*)&XH[(size_t)s0 * 128 + c0];
        uint r1 = *(const uint*)&XH[(size_t)s1 * 128 + c0];
        uint r2 = *(const uint*)&XH[(size_t)s2 * 128 + c0];
        uint r3 = *(const uint*)&XH[(size_t)s3 * 128 + c0];
        acc0 += a0 * bf2f((ushort)(r0 & 0xFFFF)); acc1 += a0 * bf2f((ushort)(r0 >> 16));
        acc0 += a1 * bf2f((ushort)(r1 & 0xFFFF)); acc1 += a1 * bf2f((ushort)(r1 >> 16));
        acc0 += a2 * bf2f((ushort)(r2 & 0xFFFF)); acc1 += a2 * bf2f((ushort)(r2 >> 16));
        acc0 += a3 * bf2f((ushort)(r3 & 0xFFFF)); acc1 += a3 * bf2f((ushort)(r3 >> 16));
    }
    for (; j < deg; ++j) {
        int b = beg + j;
        int s = csr[b];
        float a = aE[(size_t)b * NH + h];
        uint rv = *(const uint*)&XH[(size_t)s * 128 + c0];
        acc0 += a * bf2f((ushort)(rv & 0xFFFF));
        acc1 += a * bf2f((ushort)(rv >> 16));
    }
    float o0 = fmaxf(acc0 + bias[c0], 0.f);
    float o1 = fmaxf(acc1 + bias[c0 + 1], 0.f);
    uint packed = (uint)f2bf(o0) | ((uint)f2bf(o1) << 16);
    *reinterpret_cast<uint*>(&Y[(size_t)node * 128 + c0]) = packed;
}

// WD=40 fp32 (layer 3): 12 nodes per 256-thread block, 20 lanes/node.

__global__ __launch_bounds__(256) void aggregate3_f32_40(const float* __restrict__ XH,
                                                         const float* __restrict__ aE,
                                                         const float* __restrict__ aS,
                                                         const float* __restrict__ bias,
                                                         const int* __restrict__ rowptr,
                                                         const int* __restrict__ csr,
                                                         float* __restrict__ Y) {
    int t = threadIdx.x;
    int sub = t / 20, cp = t % 20;
    int node = blockIdx.x * 12 + sub;
    if (sub >= 12 || node >= N_NODES) return;
    int c0 = cp * 2;
    int beg = rowptr[node], deg = rowptr[node + 1] - beg;
    float acc0, acc1;
    {
        float a = aS[node];
        float2 x = *(const float2*)&XH[(size_t)node * 40 + c0];
        acc0 = a * x.x; acc1 = a * x.y;
    }
    int j = 0;
    for (; j + 4 <= deg; j += 4) {
        int b = beg + j;
        int s0 = csr[b], s1 = csr[b + 1], s2 = csr[b + 2], s3 = csr[b + 3];
        float a0 = aE[b], a1 = aE[b + 1], a2 = aE[b + 2], a3 = aE[b + 3];
        float2 r0 = *(const float2*)&XH[(size_t)s0 * 40 + c0];
        float2 r1 = *(const float2*)&XH[(size_t)s1 * 40 + c0];
        float2 r2 = *(const float2*)&XH[(size_t)s2 * 40 + c0];
        float2 r3 = *(const float2*)&XH[(size_t)s3 * 40 + c0];
        acc0 += a0 * r0.x; acc1 += a0 * r0.y;
        acc0 += a1 * r1.x; acc1 += a1 * r1.y;
        acc0 += a2 * r2.x; acc1 += a2 * r2.y;
        acc0 += a3 * r3.x; acc1 += a3 * r3.y;
    }
    for (; j < deg; ++j) {
        int b = beg + j;
        int s = csr[b];
        float a = aE[b];
        float2 rv = *(const float2*)&XH[(size_t)s * 40 + c0];
        acc0 += a * rv.x; acc1 += a * rv.y;
    }
    acc0 += bias[c0]; acc1 += bias[c0 + 1];
    *reinterpret_cast<float2*>(&Y[(size_t)node * 40 + c0]) = make_float2(acc0, acc1);
}

// ---------------- log-softmax over 40 classes ----------------

__global__ void logsoftmax_kernel(float* __restrict__ Y) {
    int node = (int)((blockIdx.x * blockDim.x + threadIdx.x) >> 6);
    int lane = threadIdx.x & 63;
    if (node >= N_NODES) return;
    float v = (lane < 40) ? Y[(size_t)node * 40 + lane] : -1e30f;
    float mm = v;
    #pragma unroll
    for (int off = 1; off < 64; off <<= 1) mm = fmaxf(mm, __shfl_xor(mm, off, 64));
    float p = (lane < 40) ? __expf(v - mm) : 0.f;
    #pragma unroll
    for (int off = 1; off < 64; off <<= 1) p += __shfl_xor(p, off, 64);
    float r = v - mm - __logf(p);
    if (lane < 40) Y[(size_t)node * 40 + lane] = r;
}

// ---------------- launch ----------------

static inline size_t align256(size_t x) { return (x + 255) & ~(size_t)255; }

extern "C" void kernel_launch(void* const* d_in, const int* in_sizes, int n_in,
                              void* d_out, int out_size, void* d_ws, size_t ws_size,
                              hipStream_t stream) {
    const int*   edge = (const int*)d_in[0];
    const float* feat = (const float*)d_in[1];
    const float* W1   = (const float*)d_in[2];
    const float* as1  = (const float*)d_in[3];
    const float* ad1  = (const float*)d_in[4];
    const float* b1   = (const float*)d_in[5];
    const float* W2   = (const float*)d_in[6];
    const float* as2  = (const float*)d_in[7];
    const float* ad2  = (const float*)d_in[8];
    const float* b2   = (const float*)d_in[9];
    const float* W3   = (const float*)d_in[10];
    const float* as3  = (const float*)d_in[11];
    const float* ad3  = (const float*)d_in[12];
    const float* b3   = (const float*)d_in[13];
    float* out = (float*)d_out;

    const int* srcArr = edge;
    const int* dstArr = edge + N_EDGES;

    const size_t NB128 = (size_t)N_NODES * 128 * 2;   // 25.6 MB

    char* w = (char*)d_ws;
    char* regionA = w; w += align256(2 * NB128);      // pairs (CSR build) -> a1E|a1S -> xh2|h2
    char* regionB = w; w += align256(NB128);          // xh1; later xh3 fp32 (16MB)
    char* regionC = w; w += align256(NB128);          // h1
    float* As   = (float*)w; w += align256((size_t)N_NODES * 4 * 4);
    float* Ad   = (float*)w; w += align256((size_t)N_NODES * 4 * 4);
    int* rowptr = (int*)w;   w += align256((size_t)(N_NODES + 1) * 4);
    int* csr    = (int*)w;   w += align256((size_t)N_EDGES * 4);
    int* chunkCnt  = (int*)w; w += align256((size_t)NCHUNK * NBUCK * 4);
    int* chunkBase = (int*)w; w += align256((size_t)NCHUNK * NBUCK * 4);
    int* bucketBase = (int*)w; w += align256((size_t)(NBUCK + 1) * 4);
    ushort* WT1 = (ushort*)w; w += align256((size_t)128 * 256 * 2);
    ushort* WT2 = (ushort*)w; w += align256((size_t)128 * 128 * 2);
    ushort* WT3 = (ushort*)w; w += align256((size_t)48 * 128 * 2);
    float* aEs  = (float*)w; w += align256((size_t)N_EDGES * 4);      // NH=1 edge alpha
    float* aSs  = (float*)w; w += align256((size_t)N_NODES * 4);      // NH=1 self alpha

    // pairs (12.8MB) aliases regionA: dead before a1E/a1S (stream-ordered).
    int2* pairs = (int2*)regionA;

    ushort* xh1 = (ushort*)regionB;                   // [100k][128] bf16
    ushort* h1  = (ushort*)regionC;                   // [100k][128] bf16
    float*  a1E = (float*)regionA;                    // [E][4] alpha (layer1), dead before xh2
    float*  a1S = (float*)(regionA + NB128);          // [N][4]
    ushort* xh2 = (ushort*)regionA;                   // [100k][128] bf16 (after layer1 agg)
    ushort* h2  = (ushort*)(regionA + NB128);         // [100k][128] bf16
    float*  xh3 = (float*)regionB;                    // [100k][40] fp32 (xh1 dead by then)

    // ---- CSR build: bucket counting sort ----
    bucket_hist<<<NCHUNK, 256, 0, stream>>>(dstArr, chunkCnt);
    bucket_scan<<<1, 512, 0, stream>>>(chunkCnt, chunkBase, bucketBase);
    bucket_scatter<<<NCHUNK, 256, 0, stream>>>(srcArr, dstArr, chunkBase, bucketBase, pairs);
    bucket_build<<<NBUCK, 256, 0, stream>>>(pairs, bucketBase, rowptr, csr);

    // weights
    transpose_w<<<(128 * 256 + 255) / 256, 256, 0, stream>>>(W1, WT1, 256, 128, 128);
    transpose_w<<<(128 * 128 + 255) / 256, 256, 0, stream>>>(W2, WT2, 128, 128, 128);
    transpose_w<<<(48 * 128 + 255) / 256, 256, 0, stream>>>(W3, WT3, 128, 40, 48);

    int aggGrid = (N_NODES + 3) / 4;          // wave-per-node kernels
    int gemmGrid = (N_NODES + 63) / 64;

    // ---- layer 1: 256 -> 4x32, relu ----
    mfma_gemm1<<<gemmGrid, 256, 0, stream>>>(feat, WT1, xh1);
    as_ad_bf16<128, 4, 16><<<aggGrid, 256, 0, stream>>>(xh1, as1, ad1, As, Ad);
    softmax_md4<<<aggGrid, 256, 0, stream>>>(As, Ad, rowptr, csr, a1E, a1S);
    aggregate3_bf16<4><<<aggGrid, 256, 0, stream>>>(xh1, a1E, a1S, b1, rowptr, csr, h1);

    // ---- layer 2: 128 -> 128, relu ----
    mfma_gemm_nc128<128><<<gemmGrid, 256, 0, stream>>>(h1, WT2, xh2);
    as_ad_bf16<128, 1, 64><<<aggGrid, 256, 0, stream>>>(xh2, as2, ad2, As, Ad);
    softmax_md1<<<aggGrid, 256, 0, stream>>>(As, Ad, rowptr, csr, aEs, aSs);
    aggregate3_bf16<1><<<aggGrid, 256, 0, stream>>>(xh2, aEs, aSs, b2, rowptr, csr, h2);

    // ---- layer 3: 128 -> 40 ----
    mfma_gemm_nc40<<<gemmGrid, 256, 0, stream>>>(h2, WT3, xh3);
    as_ad_f32<40, 1, 64><<<aggGrid, 256, 0, stream>>>(xh3, as3, ad3, As, Ad);
    softmax_md1<<<aggGrid, 256, 0, stream>>>(As, Ad, rowptr, csr, aEs, aSs);
    aggregate3_f32_40<<<(N_NODES + 11) / 12, 256, 0, stream>>>(xh3, aEs, aSs, b3, rowptr, csr, out);
    logsoftmax_kernel<<<aggGrid, 256, 0, stream>>>(out);
}

// Round 9
// 522.085 us; speedup vs baseline: 1.9457x; 1.0192x over previous
//
#include <hip/hip_runtime.h>
#include <cstdint>

#define N_NODES 100000
#define N_EDGES 1600000
#define NEG_SLOPE 0.2f

#define NBUCK 391          // ceil(100000/256), bucket = dst >> 8
#define NCHUNK 128
#define CHUNK_SZ ((N_EDGES + NCHUNK - 1) / NCHUNK)   // 12500

typedef short s16x8 __attribute__((ext_vector_type(8)));
typedef float f32x4 __attribute__((ext_vector_type(4)));

__device__ inline float bf2f(ushort u) {
    union { uint i; float f; } x; x.i = ((uint)u) << 16; return x.f;
}
__device__ inline ushort f2bf(float f) {
    union { float f; uint i; } x; x.f = f;
    uint r = x.i + 0x7FFF + ((x.i >> 16) & 1);   // RNE
    return (ushort)(r >> 16);
}
__device__ inline float lrelu(float e) { return (e > 0.f) ? e : NEG_SLOPE * e; }

// ---------------- CSR build: 2-level bucket counting sort ----------------

__global__ __launch_bounds__(256) void bucket_hist(const int* __restrict__ dst,
                                                   int* __restrict__ chunkCnt) {
    __shared__ int cnt[NBUCK];
    int t = threadIdx.x, blk = blockIdx.x;
    for (int b = t; b < NBUCK; b += 256) cnt[b] = 0;
    __syncthreads();
    int beg = blk * CHUNK_SZ, end = min(beg + CHUNK_SZ, N_EDGES);
    for (int i = beg + t; i < end; i += 256) atomicAdd(&cnt[dst[i] >> 8], 1);
    __syncthreads();
    for (int b = t; b < NBUCK; b += 256) chunkCnt[blk * NBUCK + b] = cnt[b];
}

__global__ __launch_bounds__(512) void bucket_scan(const int* __restrict__ chunkCnt,
                                                   int* __restrict__ chunkBase,
                                                   int* __restrict__ bucketBase) {
    __shared__ int tot[512];
    int b = threadIdx.x;
    int run = 0;
    if (b < NBUCK) {
        for (int c = 0; c < NCHUNK; ++c) {
            chunkBase[c * NBUCK + b] = run;
            run += chunkCnt[c * NBUCK + b];
        }
    }
    tot[b] = (b < NBUCK) ? run : 0;
    __syncthreads();
    for (int off = 1; off < 512; off <<= 1) {
        int x = (b >= off) ? tot[b - off] : 0;
        __syncthreads();
        tot[b] += x;
        __syncthreads();
    }
    if (b == 0) bucketBase[0] = 0;
    if (b < NBUCK) bucketBase[b + 1] = tot[b];   // inclusive -> base of b+1
}

__global__ __launch_bounds__(256) void bucket_scatter(const int* __restrict__ src,
                                                      const int* __restrict__ dst,
                                                      const int* __restrict__ chunkBase,
                                                      const int* __restrict__ bucketBase,
                                                      int2* __restrict__ pairs) {
    __shared__ int cur[NBUCK];
    int t = threadIdx.x, blk = blockIdx.x;
    for (int b = t; b < NBUCK; b += 256)
        cur[b] = bucketBase[b] + chunkBase[blk * NBUCK + b];
    __syncthreads();
    int beg = blk * CHUNK_SZ, end = min(beg + CHUNK_SZ, N_EDGES);
    for (int i = beg + t; i < end; i += 256) {
        int d = dst[i];
        int pos = atomicAdd(&cur[d >> 8], 1);
        pairs[pos] = make_int2(src[i], d);
    }
}

__global__ __launch_bounds__(256) void bucket_build(const int2* __restrict__ pairs,
                                                    const int* __restrict__ bucketBase,
                                                    int* __restrict__ rowptr,
                                                    int* __restrict__ csr) {
    __shared__ int cnt[256], pre[256];
    int b = blockIdx.x, t = threadIdx.x;
    cnt[t] = 0;
    __syncthreads();
    int beg = bucketBase[b], end = bucketBase[b + 1];
    for (int i = beg + t; i < end; i += 256) atomicAdd(&cnt[pairs[i].y & 255], 1);
    __syncthreads();
    int v = cnt[t];
    pre[t] = v;
    __syncthreads();
    for (int off = 1; off < 256; off <<= 1) {
        int x = (t >= off) ? pre[t - off] : 0;
        __syncthreads();
        pre[t] += x;
        __syncthreads();
    }
    int excl = pre[t] - v;
    int node = b * 256 + t;
    if (node <= N_NODES) rowptr[node] = beg + excl;
    cnt[t] = excl;   // reuse as cursor
    __syncthreads();
    for (int i = beg + t; i < end; i += 256) {
        int2 p = pairs[i];
        int pos = beg + atomicAdd(&cnt[p.y & 255], 1);
        csr[pos] = p.x;
    }
}

// ---------------- weight transpose/convert ----------------
__global__ void transpose_w(const float* __restrict__ W, ushort* __restrict__ BT,
                            int K, int N, int Npad) {
    int i = blockIdx.x * blockDim.x + threadIdx.x;
    if (i >= Npad * K) return;
    int n = i / K, k = i - n * K;
    float v = (n < N) ? W[(size_t)k * N + n] : 0.f;
    BT[i] = f2bf(v);
}

// ---------------- MFMA GEMM layer1: fp32 X (K=256), fused bf16 convert ----------------

__global__ __launch_bounds__(256) void mfma_gemm1(const float* __restrict__ X,
                                                  const ushort* __restrict__ BT,
                                                  ushort* __restrict__ Y) {
    __shared__ ushort As_[64][40];
    __shared__ ushort Bs[128][40];
    int m0 = blockIdx.x * 64;
    int t = threadIdx.x;
    int wave = t >> 6, lane = t & 63;
    int wm = wave >> 1, wn = wave & 1;
    f32x4 acc[2][4] = {};
    for (int kt = 0; kt < 256; kt += 32) {
        {
            int r = t >> 2, kg = (t & 3) << 3;
            int rr = (m0 + r < N_NODES) ? m0 + r : N_NODES - 1;
            float4 xa = *(const float4*)&X[(size_t)rr * 256 + kt + kg];
            float4 xb = *(const float4*)&X[(size_t)rr * 256 + kt + kg + 4];
            ushort o[8] = { f2bf(xa.x), f2bf(xa.y), f2bf(xa.z), f2bf(xa.w),
                            f2bf(xb.x), f2bf(xb.y), f2bf(xb.z), f2bf(xb.w) };
            *(s16x8*)&As_[r][kg] = *(s16x8*)o;
        }
        #pragma unroll
        for (int i = 0; i < 2; ++i) {
            int idx = t + (i << 8);
            int r = idx >> 2, kg = (idx & 3) << 3;
            *(s16x8*)&Bs[r][kg] = *(const s16x8*)&BT[(size_t)r * 256 + kt + kg];
        }
        __syncthreads();
        int row = lane & 15, koff = (lane >> 4) << 3;
        s16x8 a[2], b[4];
        #pragma unroll
        for (int mf = 0; mf < 2; ++mf)
            a[mf] = *(s16x8*)&As_[wm * 32 + mf * 16 + row][koff];
        #pragma unroll
        for (int nf = 0; nf < 4; ++nf)
            b[nf] = *(s16x8*)&Bs[wn * 64 + nf * 16 + row][koff];
        #pragma unroll
        for (int mf = 0; mf < 2; ++mf)
            #pragma unroll
            for (int nf = 0; nf < 4; ++nf)
                acc[mf][nf] = __builtin_amdgcn_mfma_f32_16x16x32_bf16(a[mf], b[nf], acc[mf][nf], 0, 0, 0);
        __syncthreads();
    }
    int colb = lane & 15, rowb = (lane >> 4) << 2;
    #pragma unroll
    for (int mf = 0; mf < 2; ++mf)
        #pragma unroll
        for (int nf = 0; nf < 4; ++nf)
            #pragma unroll
            for (int reg = 0; reg < 4; ++reg) {
                int row = m0 + wm * 32 + mf * 16 + rowb + reg;
                int col = wn * 64 + nf * 16 + colb;
                if (row < N_NODES) Y[(size_t)row * 128 + col] = f2bf(acc[mf][nf][reg]);
            }
}

// ---------------- MFMA GEMM, bf16 in, N=128 out bf16 (layer 2) ----------------

template <int K>
__global__ __launch_bounds__(256) void mfma_gemm_nc128(const ushort* __restrict__ X,
                                                       const ushort* __restrict__ BT,
                                                       ushort* __restrict__ Y) {
    __shared__ ushort As_[64][40];
    __shared__ ushort Bs[128][40];
    int m0 = blockIdx.x * 64;
    int t = threadIdx.x;
    int wave = t >> 6, lane = t & 63;
    int wm = wave >> 1, wn = wave & 1;
    f32x4 acc[2][4] = {};
    for (int kt = 0; kt < K; kt += 32) {
        {
            int r = t >> 2, kg = (t & 3) << 3;
            *(s16x8*)&As_[r][kg] = *(const s16x8*)&X[(size_t)(m0 + r) * K + kt + kg];
        }
        #pragma unroll
        for (int i = 0; i < 2; ++i) {
            int idx = t + (i << 8);
            int r = idx >> 2, kg = (idx & 3) << 3;
            *(s16x8*)&Bs[r][kg] = *(const s16x8*)&BT[(size_t)r * K + kt + kg];
        }
        __syncthreads();
        int row = lane & 15, koff = (lane >> 4) << 3;
        s16x8 a[2], b[4];
        #pragma unroll
        for (int mf = 0; mf < 2; ++mf)
            a[mf] = *(s16x8*)&As_[wm * 32 + mf * 16 + row][koff];
        #pragma unroll
        for (int nf = 0; nf < 4; ++nf)
            b[nf] = *(s16x8*)&Bs[wn * 64 + nf * 16 + row][koff];
        #pragma unroll
        for (int mf = 0; mf < 2; ++mf)
            #pragma unroll
            for (int nf = 0; nf < 4; ++nf)
                acc[mf][nf] = __builtin_amdgcn_mfma_f32_16x16x32_bf16(a[mf], b[nf], acc[mf][nf], 0, 0, 0);
        __syncthreads();
    }
    int colb = lane & 15, rowb = (lane >> 4) << 2;
    #pragma unroll
    for (int mf = 0; mf < 2; ++mf)
        #pragma unroll
        for (int nf = 0; nf < 4; ++nf)
            #pragma unroll
            for (int reg = 0; reg < 4; ++reg) {
                int row = m0 + wm * 32 + mf * 16 + rowb + reg;
                int col = wn * 64 + nf * 16 + colb;
                if (row < N_NODES) Y[(size_t)row * 128 + col] = f2bf(acc[mf][nf][reg]);
            }
}

// ---------------- MFMA GEMM, K=128, N=40 (padded 48), bf16 out stride 64 ----------------

__global__ __launch_bounds__(256) void mfma_gemm_nc40(const ushort* __restrict__ X,
                                                      const ushort* __restrict__ BT,
                                                      ushort* __restrict__ Y) {
    __shared__ ushort As_[64][40];
    __shared__ ushort Bs[48][40];
    int m0 = blockIdx.x * 64;
    int t = threadIdx.x, wave = t >> 6, lane = t & 63;
    f32x4 acc[3] = {};
    for (int kt = 0; kt < 128; kt += 32) {
        {
            int r = t >> 2, kg = (t & 3) << 3;
            *(s16x8*)&As_[r][kg] = *(const s16x8*)&X[(size_t)(m0 + r) * 128 + kt + kg];
        }
        if (t < 192) {
            int r = t >> 2, kg = (t & 3) << 3;
            *(s16x8*)&Bs[r][kg] = *(const s16x8*)&BT[(size_t)r * 128 + kt + kg];
        }
        __syncthreads();
        int row = lane & 15, koff = (lane >> 4) << 3;
        s16x8 a = *(s16x8*)&As_[wave * 16 + row][koff];
        #pragma unroll
        for (int nf = 0; nf < 3; ++nf) {
            s16x8 b = *(s16x8*)&Bs[nf * 16 + row][koff];
            acc[nf] = __builtin_amdgcn_mfma_f32_16x16x32_bf16(a, b, acc[nf], 0, 0, 0);
        }
        __syncthreads();
    }
    int colb = lane & 15, rowb = (lane >> 4) << 2;
    #pragma unroll
    for (int nf = 0; nf < 3; ++nf)
        #pragma unroll
        for (int reg = 0; reg < 4; ++reg) {
            int row = m0 + wave * 16 + rowb + reg;
            int col = nf * 16 + colb;
            if (row < N_NODES) Y[(size_t)row * 64 + col] = f2bf(acc[nf][reg]);
        }
}

// ---------------- attention coefficients ----------------

template <int WD, int NH, int SEG>
__global__ void as_ad_bf16(const ushort* __restrict__ XH, const float* __restrict__ asrc,
                           const float* __restrict__ adst, float* __restrict__ As,
                           float* __restrict__ Ad) {
    int node = (int)((blockIdx.x * blockDim.x + threadIdx.x) >> 6);
    int lane = threadIdx.x & 63;
    if (node >= N_NODES) return;
    int c0 = lane * 2;
    uint xv = *reinterpret_cast<const uint*>(&XH[(size_t)node * WD + c0]);
    float x0 = bf2f((ushort)(xv & 0xFFFF)), x1 = bf2f((ushort)(xv >> 16));
    float2 a = *reinterpret_cast<const float2*>(&asrc[c0]);
    float2 b = *reinterpret_cast<const float2*>(&adst[c0]);
    float s = x0 * a.x + x1 * a.y;
    float d = x0 * b.x + x1 * b.y;
    #pragma unroll
    for (int off = 1; off < SEG; off <<= 1) {
        s += __shfl_xor(s, off, 64);
        d += __shfl_xor(d, off, 64);
    }
    if ((lane % SEG) == 0) {
        int h = c0 / (WD / NH);
        As[(size_t)node * NH + h] = s;
        Ad[(size_t)node * NH + h] = d;
    }
}

// layer 3: rows stride 64 bf16, 40 valid cols; a vectors have 40 entries.
__global__ void as_ad_w64_40(const ushort* __restrict__ XH, const float* __restrict__ asrc,
                             const float* __restrict__ adst, float* __restrict__ As,
                             float* __restrict__ Ad) {
    int node = (int)((blockIdx.x * blockDim.x + threadIdx.x) >> 6);
    int lane = threadIdx.x & 63;
    if (node >= N_NODES) return;
    int c0 = lane * 2;
    float s = 0.f, d = 0.f;
    if (c0 < 40) {
        uint xv = *reinterpret_cast<const uint*>(&XH[(size_t)node * 64 + c0]);
        float x0 = bf2f((ushort)(xv & 0xFFFF)), x1 = bf2f((ushort)(xv >> 16));
        float2 a = *reinterpret_cast<const float2*>(&asrc[c0]);
        float2 b = *reinterpret_cast<const float2*>(&adst[c0]);
        s = x0 * a.x + x1 * a.y;
        d = x0 * b.x + x1 * b.y;
    }
    #pragma unroll
    for (int off = 1; off < 64; off <<= 1) {
        s += __shfl_xor(s, off, 64);
        d += __shfl_xor(d, off, 64);
    }
    if (lane == 0) { As[node] = s; Ad[node] = d; }
}

// ---------------- softmax scalars ----------------

__global__ void softmax_md1(const float* __restrict__ As, const float* __restrict__ Ad,
                            const int* __restrict__ rowptr, const int* __restrict__ csr,
                            float* __restrict__ aE, float* __restrict__ aS) {
    int node = (int)((blockIdx.x * blockDim.x + threadIdx.x) >> 6);
    int lane = threadIdx.x & 63;
    if (node >= N_NODES) return;
    int beg = rowptr[node], deg = rowptr[node + 1] - beg;
    float adi = Ad[node];
    float m = -1e30f;
    for (int i = lane; i <= deg; i += 64) {
        int src = (i < deg) ? csr[beg + i] : node;
        m = fmaxf(m, lrelu(As[src] + adi));
    }
    #pragma unroll
    for (int off = 1; off < 64; off <<= 1) m = fmaxf(m, __shfl_xor(m, off, 64));
    float den = 0.f;
    for (int i = lane; i <= deg; i += 64) {
        int src = (i < deg) ? csr[beg + i] : node;
        den += __expf(lrelu(As[src] + adi) - m);
    }
    #pragma unroll
    for (int off = 1; off < 64; off <<= 1) den += __shfl_xor(den, off, 64);
    float dinv = 1.0f / den;
    for (int i = lane; i <= deg; i += 64) {
        int src = (i < deg) ? csr[beg + i] : node;
        float a = __expf(lrelu(As[src] + adi) - m) * dinv;
        if (i < deg) aE[beg + i] = a; else aS[node] = a;
    }
}

__global__ void softmax_md4(const float* __restrict__ As, const float* __restrict__ Ad,
                            const int* __restrict__ rowptr, const int* __restrict__ csr,
                            float* __restrict__ aE, float* __restrict__ aS) {
    int node = (int)((blockIdx.x * blockDim.x + threadIdx.x) >> 6);
    int lane = threadIdx.x & 63;
    if (node >= N_NODES) return;
    int h = lane & 3, il = lane >> 2;
    int beg = rowptr[node], deg = rowptr[node + 1] - beg;
    float adi = Ad[(size_t)node * 4 + h];
    float m = -1e30f;
    for (int i = il; i <= deg; i += 16) {
        int src = (i < deg) ? csr[beg + i] : node;
        m = fmaxf(m, lrelu(As[(size_t)src * 4 + h] + adi));
    }
    #pragma unroll
    for (int off = 4; off < 64; off <<= 1) m = fmaxf(m, __shfl_xor(m, off, 64));
    float den = 0.f;
    for (int i = il; i <= deg; i += 16) {
        int src = (i < deg) ? csr[beg + i] : node;
        den += __expf(lrelu(As[(size_t)src * 4 + h] + adi) - m);
    }
    #pragma unroll
    for (int off = 4; off < 64; off <<= 1) den += __shfl_xor(den, off, 64);
    float dinv = 1.0f / den;
    for (int i = il; i <= deg; i += 16) {
        int src = (i < deg) ? csr[beg + i] : node;
        float a = __expf(lrelu(As[(size_t)src * 4 + h] + adi) - m) * dinv;
        if (i < deg) aE[(size_t)(beg + i) * 4 + h] = a;
        else aS[(size_t)node * 4 + h] = a;
    }
}

// ---------------- aggregation: 16B/lane gathers, 4 rows per wave-round ----------------

template <int NH>
__global__ void aggregate4_bf16(const ushort* __restrict__ XH, const float* __restrict__ aE,
                                const float* __restrict__ aS, const float* __restrict__ bias,
                                const int* __restrict__ rowptr, const int* __restrict__ csr,
                                ushort* __restrict__ Y) {
    int node = (int)((blockIdx.x * blockDim.x + threadIdx.x) >> 6);
    int lane = threadIdx.x & 63;
    if (node >= N_NODES) return;
    int sub = lane >> 4;            // 0..3: row within round
    int cg = (lane & 15) << 3;      // col group: 8 bf16 = 16B
    int h = (NH == 4) ? (cg >> 5) : 0;
    int beg = rowptr[node], deg = rowptr[node + 1] - beg;
    int items = deg + 1;            // + self loop
    float acc[8] = {};
    for (int base = 0; base < items; base += 4) {
        int i = base + sub;
        int src; float a;
        if (i < deg)       { int idx = beg + i; src = csr[idx]; a = aE[(size_t)idx * NH + h]; }
        else if (i == deg) { src = node; a = aS[(size_t)node * NH + h]; }
        else               { src = node; a = 0.f; }
        uint4 rv = *(const uint4*)&XH[(size_t)src * 128 + cg];
        uint rw[4] = { rv.x, rv.y, rv.z, rv.w };
        #pragma unroll
        for (int k = 0; k < 4; ++k) {
            acc[2 * k]     += a * bf2f((ushort)(rw[k] & 0xFFFF));
            acc[2 * k + 1] += a * bf2f((ushort)(rw[k] >> 16));
        }
    }
    #pragma unroll
    for (int k = 0; k < 8; ++k) {
        acc[k] += __shfl_xor(acc[k], 16, 64);
        acc[k] += __shfl_xor(acc[k], 32, 64);
    }
    if (sub == 0) {                 // lanes 0..15 write cols cg..cg+7
        uint o[4];
        #pragma unroll
        for (int k = 0; k < 4; ++k) {
            float v0 = fmaxf(acc[2 * k]     + bias[cg + 2 * k],     0.f);
            float v1 = fmaxf(acc[2 * k + 1] + bias[cg + 2 * k + 1], 0.f);
            o[k] = (uint)f2bf(v0) | ((uint)f2bf(v1) << 16);
        }
        *reinterpret_cast<uint4*>(&Y[(size_t)node * 128 + cg]) = *reinterpret_cast<uint4*>(o);
    }
}

// layer 3: bf16 rows stride 64 (128B), 8 rows per wave-round; fp32 out, 40 cols, no relu.
__global__ void aggregate4_w64_f32(const ushort* __restrict__ XH, const float* __restrict__ aE,
                                   const float* __restrict__ aS, const float* __restrict__ bias,
                                   const int* __restrict__ rowptr, const int* __restrict__ csr,
                                   float* __restrict__ Y) {
    int node = (int)((blockIdx.x * blockDim.x + threadIdx.x) >> 6);
    int lane = threadIdx.x & 63;
    if (node >= N_NODES) return;
    int sub = lane >> 3;            // 0..7: row within round
    int cg = (lane & 7) << 3;       // col group: 8 bf16 = 16B
    int beg = rowptr[node], deg = rowptr[node + 1] - beg;
    int items = deg + 1;
    float acc[8] = {};
    for (int base = 0; base < items; base += 8) {
        int i = base + sub;
        int src; float a;
        if (i < deg)       { int idx = beg + i; src = csr[idx]; a = aE[idx]; }
        else if (i == deg) { src = node; a = aS[node]; }
        else               { src = node; a = 0.f; }
        uint4 rv = *(const uint4*)&XH[(size_t)src * 64 + cg];
        uint rw[4] = { rv.x, rv.y, rv.z, rv.w };
        #pragma unroll
        for (int k = 0; k < 4; ++k) {
            acc[2 * k]     += a * bf2f((ushort)(rw[k] & 0xFFFF));
            acc[2 * k + 1] += a * bf2f((ushort)(rw[k] >> 16));
        }
    }
    #pragma unroll
    for (int k = 0; k < 8; ++k) {
        acc[k] += __shfl_xor(acc[k], 8, 64);
        acc[k] += __shfl_xor(acc[k], 16, 64);
        acc[k] += __shfl_xor(acc[k], 32, 64);
    }
    if (lane < 5) {                 // lanes 0..4 write cols cg..cg+7 (cols < 40)
        float4 o0 = make_float4(acc[0] + bias[cg], acc[1] + bias[cg + 1],
                                acc[2] + bias[cg + 2], acc[3] + bias[cg + 3]);
        float4 o1 = make_float4(acc[4] + bias[cg + 4], acc[5] + bias[cg + 5],
                                acc[6] + bias[cg + 6], acc[7] + bias[cg + 7]);
        *reinterpret_cast<float4*>(&Y[(size_t)node * 40 + cg]) = o0;
        *reinterpret_cast<float4*>(&Y[(size_t)node * 40 + cg + 4]) = o1;
    }
}

// ---------------- log-softmax over 40 classes ----------------

__global__ void logsoftmax_kernel(float* __restrict__ Y) {
    int node = (int)((blockIdx.x * blockDim.x + threadIdx.x) >> 6);
    int lane = threadIdx.x & 63;
    if (node >= N_NODES) return;
    float v = (lane < 40) ? Y[(size_t)node * 40 + lane] : -1e30f;
    float mm = v;
    #pragma unroll
    for (int off = 1; off < 64; off <<= 1) mm = fmaxf(mm, __shfl_xor(mm, off, 64));
    float p = (lane < 40) ? __expf(v - mm) : 0.f;
    #pragma unroll
    for (int off = 1; off < 64; off <<= 1) p += __shfl_xor(p, off, 64);
    float r = v - mm - __logf(p);
    if (lane < 40) Y[(size_t)node * 40 + lane] = r;
}

// ---------------- launch ----------------

static inline size_t align256(size_t x) { return (x + 255) & ~(size_t)255; }

extern "C" void kernel_launch(void* const* d_in, const int* in_sizes, int n_in,
                              void* d_out, int out_size, void* d_ws, size_t ws_size,
                              hipStream_t stream) {
    const int*   edge = (const int*)d_in[0];
    const float* feat = (const float*)d_in[1];
    const float* W1   = (const float*)d_in[2];
    const float* as1  = (const float*)d_in[3];
    const float* ad1  = (const float*)d_in[4];
    const float* b1   = (const float*)d_in[5];
    const float* W2   = (const float*)d_in[6];
    const float* as2  = (const float*)d_in[7];
    const float* ad2  = (const float*)d_in[8];
    const float* b2   = (const float*)d_in[9];
    const float* W3   = (const float*)d_in[10];
    const float* as3  = (const float*)d_in[11];
    const float* ad3  = (const float*)d_in[12];
    const float* b3   = (const float*)d_in[13];
    float* out = (float*)d_out;

    const int* srcArr = edge;
    const int* dstArr = edge + N_EDGES;

    const size_t NB128 = (size_t)N_NODES * 128 * 2;   // 25.6 MB

    char* w = (char*)d_ws;
    char* regionA = w; w += align256(2 * NB128);      // pairs -> a1E|a1S -> xh2|h2
    char* regionB = w; w += align256(NB128);          // xh1; later xh3 bf16 [100k][64]
    char* regionC = w; w += align256(NB128);          // h1
    float* As   = (float*)w; w += align256((size_t)N_NODES * 4 * 4);
    float* Ad   = (float*)w; w += align256((size_t)N_NODES * 4 * 4);
    int* rowptr = (int*)w;   w += align256((size_t)(N_NODES + 1) * 4);
    int* csr    = (int*)w;   w += align256((size_t)N_EDGES * 4);
    int* chunkCnt  = (int*)w; w += align256((size_t)NCHUNK * NBUCK * 4);
    int* chunkBase = (int*)w; w += align256((size_t)NCHUNK * NBUCK * 4);
    int* bucketBase = (int*)w; w += align256((size_t)(NBUCK + 1) * 4);
    ushort* WT1 = (ushort*)w; w += align256((size_t)128 * 256 * 2);
    ushort* WT2 = (ushort*)w; w += align256((size_t)128 * 128 * 2);
    ushort* WT3 = (ushort*)w; w += align256((size_t)48 * 128 * 2);
    float* aEs  = (float*)w; w += align256((size_t)N_EDGES * 4);
    float* aSs  = (float*)w; w += align256((size_t)N_NODES * 4);

    int2* pairs = (int2*)regionA;                     // dead before a1E/a1S

    ushort* xh1 = (ushort*)regionB;                   // [100k][128] bf16
    ushort* h1  = (ushort*)regionC;                   // [100k][128] bf16
    float*  a1E = (float*)regionA;                    // [E][4], dead before xh2
    float*  a1S = (float*)(regionA + NB128);          // [N][4]
    ushort* xh2 = (ushort*)regionA;                   // [100k][128] bf16
    ushort* h2  = (ushort*)(regionA + NB128);         // [100k][128] bf16
    ushort* xh3 = (ushort*)regionB;                   // [100k][64] bf16 (xh1 dead)

    // ---- CSR build ----
    bucket_hist<<<NCHUNK, 256, 0, stream>>>(dstArr, chunkCnt);
    bucket_scan<<<1, 512, 0, stream>>>(chunkCnt, chunkBase, bucketBase);
    bucket_scatter<<<NCHUNK, 256, 0, stream>>>(srcArr, dstArr, chunkBase, bucketBase, pairs);
    bucket_build<<<NBUCK, 256, 0, stream>>>(pairs, bucketBase, rowptr, csr);

    // weights
    transpose_w<<<(128 * 256 + 255) / 256, 256, 0, stream>>>(W1, WT1, 256, 128, 128);
    transpose_w<<<(128 * 128 + 255) / 256, 256, 0, stream>>>(W2, WT2, 128, 128, 128);
    transpose_w<<<(48 * 128 + 255) / 256, 256, 0, stream>>>(W3, WT3, 128, 40, 48);

    int aggGrid = (N_NODES + 3) / 4;
    int gemmGrid = (N_NODES + 63) / 64;

    // ---- layer 1 ----
    mfma_gemm1<<<gemmGrid, 256, 0, stream>>>(feat, WT1, xh1);
    as_ad_bf16<128, 4, 16><<<aggGrid, 256, 0, stream>>>(xh1, as1, ad1, As, Ad);
    softmax_md4<<<aggGrid, 256, 0, stream>>>(As, Ad, rowptr, csr, a1E, a1S);
    aggregate4_bf16<4><<<aggGrid, 256, 0, stream>>>(xh1, a1E, a1S, b1, rowptr, csr, h1);

    // ---- layer 2 ----
    mfma_gemm_nc128<128><<<gemmGrid, 256, 0, stream>>>(h1, WT2, xh2);
    as_ad_bf16<128, 1, 64><<<aggGrid, 256, 0, stream>>>(xh2, as2, ad2, As, Ad);
    softmax_md1<<<aggGrid, 256, 0, stream>>>(As, Ad, rowptr, csr, aEs, aSs);
    aggregate4_bf16<1><<<aggGrid, 256, 0, stream>>>(xh2, aEs, aSs, b2, rowptr, csr, h2);

    // ---- layer 3 ----
    mfma_gemm_nc40<<<gemmGrid, 256, 0, stream>>>(h2, WT3, xh3);
    as_ad_w64_40<<<aggGrid, 256, 0, stream>>>(xh3, as3, ad3, As, Ad);
    softmax_md1<<<aggGrid, 256, 0, stream>>>(As, Ad, rowptr, csr, aEs, aSs);
    aggregate4_w64_f32<<<aggGrid, 256, 0, stream>>>(xh3, aEs, aSs, b3, rowptr, csr, out);
    logsoftmax_kernel<<<aggGrid, 256, 0, stream>>>(out);
}

// Round 10
// 449.406 us; speedup vs baseline: 2.2603x; 1.1617x over previous
//
#include <hip/hip_runtime.h>
#include <cstdint>

#define N_NODES 100000
#define N_EDGES 1600000
#define NEG_SLOPE 0.2f

#define NBUCK 391          // ceil(100000/256), bucket = dst >> 8
#define NCHUNK 128
#define CHUNK_SZ ((N_EDGES + NCHUNK - 1) / NCHUNK)   // 12500

typedef short s16x8 __attribute__((ext_vector_type(8)));
typedef float f32x4 __attribute__((ext_vector_type(4)));

__device__ inline float bf2f(ushort u) {
    union { uint i; float f; } x; x.i = ((uint)u) << 16; return x.f;
}
__device__ inline ushort f2bf(float f) {
    union { float f; uint i; } x; x.f = f;
    uint r = x.i + 0x7FFF + ((x.i >> 16) & 1);   // RNE
    return (ushort)(r >> 16);
}
__device__ inline float lrelu(float e) { return (e > 0.f) ? e : NEG_SLOPE * e; }

// ---------------- CSR build: 2-level bucket counting sort (packed pairs) ----------------

__global__ __launch_bounds__(256) void bucket_hist(const int* __restrict__ dst,
                                                   int* __restrict__ chunkCnt) {
    __shared__ int cnt[NBUCK];
    int t = threadIdx.x, blk = blockIdx.x;
    for (int b = t; b < NBUCK; b += 256) cnt[b] = 0;
    __syncthreads();
    int beg = blk * CHUNK_SZ, end = min(beg + CHUNK_SZ, N_EDGES);
    for (int i = beg + t; i < end; i += 256) atomicAdd(&cnt[dst[i] >> 8], 1);
    __syncthreads();
    for (int b = t; b < NBUCK; b += 256) chunkCnt[blk * NBUCK + b] = cnt[b];
}

__global__ __launch_bounds__(512) void bucket_scan(const int* __restrict__ chunkCnt,
                                                   int* __restrict__ chunkBase,
                                                   int* __restrict__ bucketBase) {
    __shared__ int tot[512];
    int b = threadIdx.x;
    int run = 0;
    if (b < NBUCK) {
        for (int c = 0; c < NCHUNK; ++c) {
            chunkBase[c * NBUCK + b] = run;
            run += chunkCnt[c * NBUCK + b];
        }
    }
    tot[b] = (b < NBUCK) ? run : 0;
    __syncthreads();
    for (int off = 1; off < 512; off <<= 1) {
        int x = (b >= off) ? tot[b - off] : 0;
        __syncthreads();
        tot[b] += x;
        __syncthreads();
    }
    if (b == 0) bucketBase[0] = 0;
    if (b < NBUCK) bucketBase[b + 1] = tot[b];   // inclusive -> base of b+1
}

// packed pair: (src << 8) | (dst & 255); src < 2^17 so fits in 25 bits.
__global__ __launch_bounds__(256) void bucket_scatter(const int* __restrict__ src,
                                                      const int* __restrict__ dst,
                                                      const int* __restrict__ chunkBase,
                                                      const int* __restrict__ bucketBase,
                                                      int* __restrict__ pairs) {
    __shared__ int cur[NBUCK];
    int t = threadIdx.x, blk = blockIdx.x;
    for (int b = t; b < NBUCK; b += 256)
        cur[b] = bucketBase[b] + chunkBase[blk * NBUCK + b];
    __syncthreads();
    int beg = blk * CHUNK_SZ, end = min(beg + CHUNK_SZ, N_EDGES);
    for (int i = beg + t; i < end; i += 256) {
        int d = dst[i];
        int pos = atomicAdd(&cur[d >> 8], 1);
        pairs[pos] = (src[i] << 8) | (d & 255);
    }
}

__global__ __launch_bounds__(256) void bucket_build(const int* __restrict__ pairs,
                                                    const int* __restrict__ bucketBase,
                                                    int* __restrict__ rowptr,
                                                    int* __restrict__ csr) {
    __shared__ int cnt[256], pre[256];
    int b = blockIdx.x, t = threadIdx.x;
    cnt[t] = 0;
    __syncthreads();
    int beg = bucketBase[b], end = bucketBase[b + 1];
    for (int i = beg + t; i < end; i += 256) atomicAdd(&cnt[pairs[i] & 255], 1);
    __syncthreads();
    int v = cnt[t];
    pre[t] = v;
    __syncthreads();
    for (int off = 1; off < 256; off <<= 1) {
        int x = (t >= off) ? pre[t - off] : 0;
        __syncthreads();
        pre[t] += x;
        __syncthreads();
    }
    int excl = pre[t] - v;
    int node = b * 256 + t;
    if (node <= N_NODES) rowptr[node] = beg + excl;
    cnt[t] = excl;   // reuse as cursor
    __syncthreads();
    for (int i = beg + t; i < end; i += 256) {
        int p = pairs[i];
        int pos = beg + atomicAdd(&cnt[p & 255], 1);
        csr[pos] = p >> 8;
    }
}

// ---------------- weight transpose/convert ----------------
__global__ void transpose_w(const float* __restrict__ W, ushort* __restrict__ BT,
                            int K, int N, int Npad) {
    int i = blockIdx.x * blockDim.x + threadIdx.x;
    if (i >= Npad * K) return;
    int n = i / K, k = i - n * K;
    float v = (n < N) ? W[(size_t)k * N + n] : 0.f;
    BT[i] = f2bf(v);
}

// ---------------- MFMA GEMM layer1: fp32 X (K=256), fused bf16 convert ----------------

__global__ __launch_bounds__(256) void mfma_gemm1(const float* __restrict__ X,
                                                  const ushort* __restrict__ BT,
                                                  ushort* __restrict__ Y) {
    __shared__ ushort As_[64][40];
    __shared__ ushort Bs[128][40];
    int m0 = blockIdx.x * 64;
    int t = threadIdx.x;
    int wave = t >> 6, lane = t & 63;
    int wm = wave >> 1, wn = wave & 1;
    f32x4 acc[2][4] = {};
    for (int kt = 0; kt < 256; kt += 32) {
        {
            int r = t >> 2, kg = (t & 3) << 3;
            int rr = (m0 + r < N_NODES) ? m0 + r : N_NODES - 1;
            float4 xa = *(const float4*)&X[(size_t)rr * 256 + kt + kg];
            float4 xb = *(const float4*)&X[(size_t)rr * 256 + kt + kg + 4];
            ushort o[8] = { f2bf(xa.x), f2bf(xa.y), f2bf(xa.z), f2bf(xa.w),
                            f2bf(xb.x), f2bf(xb.y), f2bf(xb.z), f2bf(xb.w) };
            *(s16x8*)&As_[r][kg] = *(s16x8*)o;
        }
        #pragma unroll
        for (int i = 0; i < 2; ++i) {
            int idx = t + (i << 8);
            int r = idx >> 2, kg = (idx & 3) << 3;
            *(s16x8*)&Bs[r][kg] = *(const s16x8*)&BT[(size_t)r * 256 + kt + kg];
        }
        __syncthreads();
        int row = lane & 15, koff = (lane >> 4) << 3;
        s16x8 a[2], b[4];
        #pragma unroll
        for (int mf = 0; mf < 2; ++mf)
            a[mf] = *(s16x8*)&As_[wm * 32 + mf * 16 + row][koff];
        #pragma unroll
        for (int nf = 0; nf < 4; ++nf)
            b[nf] = *(s16x8*)&Bs[wn * 64 + nf * 16 + row][koff];
        #pragma unroll
        for (int mf = 0; mf < 2; ++mf)
            #pragma unroll
            for (int nf = 0; nf < 4; ++nf)
                acc[mf][nf] = __builtin_amdgcn_mfma_f32_16x16x32_bf16(a[mf], b[nf], acc[mf][nf], 0, 0, 0);
        __syncthreads();
    }
    int colb = lane & 15, rowb = (lane >> 4) << 2;
    #pragma unroll
    for (int mf = 0; mf < 2; ++mf)
        #pragma unroll
        for (int nf = 0; nf < 4; ++nf)
            #pragma unroll
            for (int reg = 0; reg < 4; ++reg) {
                int row = m0 + wm * 32 + mf * 16 + rowb + reg;
                int col = wn * 64 + nf * 16 + colb;
                if (row < N_NODES) Y[(size_t)row * 128 + col] = f2bf(acc[mf][nf][reg]);
            }
}

// ---------------- MFMA GEMM, bf16 in, N=128 out bf16 (layer 2) ----------------

template <int K>
__global__ __launch_bounds__(256) void mfma_gemm_nc128(const ushort* __restrict__ X,
                                                       const ushort* __restrict__ BT,
                                                       ushort* __restrict__ Y) {
    __shared__ ushort As_[64][40];
    __shared__ ushort Bs[128][40];
    int m0 = blockIdx.x * 64;
    int t = threadIdx.x;
    int wave = t >> 6, lane = t & 63;
    int wm = wave >> 1, wn = wave & 1;
    f32x4 acc[2][4] = {};
    for (int kt = 0; kt < K; kt += 32) {
        {
            int r = t >> 2, kg = (t & 3) << 3;
            *(s16x8*)&As_[r][kg] = *(const s16x8*)&X[(size_t)(m0 + r) * K + kt + kg];
        }
        #pragma unroll
        for (int i = 0; i < 2; ++i) {
            int idx = t + (i << 8);
            int r = idx >> 2, kg = (idx & 3) << 3;
            *(s16x8*)&Bs[r][kg] = *(const s16x8*)&BT[(size_t)r * K + kt + kg];
        }
        __syncthreads();
        int row = lane & 15, koff = (lane >> 4) << 3;
        s16x8 a[2], b[4];
        #pragma unroll
        for (int mf = 0; mf < 2; ++mf)
            a[mf] = *(s16x8*)&As_[wm * 32 + mf * 16 + row][koff];
        #pragma unroll
        for (int nf = 0; nf < 4; ++nf)
            b[nf] = *(s16x8*)&Bs[wn * 64 + nf * 16 + row][koff];
        #pragma unroll
        for (int mf = 0; mf < 2; ++mf)
            #pragma unroll
            for (int nf = 0; nf < 4; ++nf)
                acc[mf][nf] = __builtin_amdgcn_mfma_f32_16x16x32_bf16(a[mf], b[nf], acc[mf][nf], 0, 0, 0);
        __syncthreads();
    }
    int colb = lane & 15, rowb = (lane >> 4) << 2;
    #pragma unroll
    for (int mf = 0; mf < 2; ++mf)
        #pragma unroll
        for (int nf = 0; nf < 4; ++nf)
            #pragma unroll
            for (int reg = 0; reg < 4; ++reg) {
                int row = m0 + wm * 32 + mf * 16 + rowb + reg;
                int col = wn * 64 + nf * 16 + colb;
                if (row < N_NODES) Y[(size_t)row * 128 + col] = f2bf(acc[mf][nf][reg]);
            }
}

// ---------------- MFMA GEMM, K=128, N=40 (padded 48), bf16 out stride 64 ----------------

__global__ __launch_bounds__(256) void mfma_gemm_nc40(const ushort* __restrict__ X,
                                                      const ushort* __restrict__ BT,
                                                      ushort* __restrict__ Y) {
    __shared__ ushort As_[64][40];
    __shared__ ushort Bs[48][40];
    int m0 = blockIdx.x * 64;
    int t = threadIdx.x, wave = t >> 6, lane = t & 63;
    f32x4 acc[3] = {};
    for (int kt = 0; kt < 128; kt += 32) {
        {
            int r = t >> 2, kg = (t & 3) << 3;
            *(s16x8*)&As_[r][kg] = *(const s16x8*)&X[(size_t)(m0 + r) * 128 + kt + kg];
        }
        if (t < 192) {
            int r = t >> 2, kg = (t & 3) << 3;
            *(s16x8*)&Bs[r][kg] = *(const s16x8*)&BT[(size_t)r * 128 + kt + kg];
        }
        __syncthreads();
        int row = lane & 15, koff = (lane >> 4) << 3;
        s16x8 a = *(s16x8*)&As_[wave * 16 + row][koff];
        #pragma unroll
        for (int nf = 0; nf < 3; ++nf) {
            s16x8 b = *(s16x8*)&Bs[nf * 16 + row][koff];
            acc[nf] = __builtin_amdgcn_mfma_f32_16x16x32_bf16(a, b, acc[nf], 0, 0, 0);
        }
        __syncthreads();
    }
    int colb = lane & 15, rowb = (lane >> 4) << 2;
    #pragma unroll
    for (int nf = 0; nf < 3; ++nf)
        #pragma unroll
        for (int reg = 0; reg < 4; ++reg) {
            int row = m0 + wave * 16 + rowb + reg;
            int col = nf * 16 + colb;
            if (row < N_NODES) Y[(size_t)row * 64 + col] = f2bf(acc[nf][reg]);
        }
}

// ---------------- attention coefficients ----------------

template <int WD, int NH, int SEG>
__global__ void as_ad_bf16(const ushort* __restrict__ XH, const float* __restrict__ asrc,
                           const float* __restrict__ adst, float* __restrict__ As,
                           float* __restrict__ Ad) {
    int node = (int)((blockIdx.x * blockDim.x + threadIdx.x) >> 6);
    int lane = threadIdx.x & 63;
    if (node >= N_NODES) return;
    int c0 = lane * 2;
    uint xv = *reinterpret_cast<const uint*>(&XH[(size_t)node * WD + c0]);
    float x0 = bf2f((ushort)(xv & 0xFFFF)), x1 = bf2f((ushort)(xv >> 16));
    float2 a = *reinterpret_cast<const float2*>(&asrc[c0]);
    float2 b = *reinterpret_cast<const float2*>(&adst[c0]);
    float s = x0 * a.x + x1 * a.y;
    float d = x0 * b.x + x1 * b.y;
    #pragma unroll
    for (int off = 1; off < SEG; off <<= 1) {
        s += __shfl_xor(s, off, 64);
        d += __shfl_xor(d, off, 64);
    }
    if ((lane % SEG) == 0) {
        int h = c0 / (WD / NH);
        As[(size_t)node * NH + h] = s;
        Ad[(size_t)node * NH + h] = d;
    }
}

// layer 3: rows stride 64 bf16, 40 valid cols.
__global__ void as_ad_w64_40(const ushort* __restrict__ XH, const float* __restrict__ asrc,
                             const float* __restrict__ adst, float* __restrict__ As,
                             float* __restrict__ Ad) {
    int node = (int)((blockIdx.x * blockDim.x + threadIdx.x) >> 6);
    int lane = threadIdx.x & 63;
    if (node >= N_NODES) return;
    int c0 = lane * 2;
    float s = 0.f, d = 0.f;
    if (c0 < 40) {
        uint xv = *reinterpret_cast<const uint*>(&XH[(size_t)node * 64 + c0]);
        float x0 = bf2f((ushort)(xv & 0xFFFF)), x1 = bf2f((ushort)(xv >> 16));
        float2 a = *reinterpret_cast<const float2*>(&asrc[c0]);
        float2 b = *reinterpret_cast<const float2*>(&adst[c0]);
        s = x0 * a.x + x1 * a.y;
        d = x0 * b.x + x1 * b.y;
    }
    #pragma unroll
    for (int off = 1; off < 64; off <<= 1) {
        s += __shfl_xor(s, off, 64);
        d += __shfl_xor(d, off, 64);
    }
    if (lane == 0) { As[node] = s; Ad[node] = d; }
}

// ---------------- fused softmax + aggregate (WD=128 bf16) ----------------
// Phase A: per-node max + denom (shuffle reduce). Phase B: weighted 16B/lane gather
// with alpha computed inline. NH=1 or 4.

template <int NH>
__global__ void agg_fused_bf16(const ushort* __restrict__ XH, const float* __restrict__ As,
                               const float* __restrict__ Ad, const float* __restrict__ bias,
                               const int* __restrict__ rowptr, const int* __restrict__ csr,
                               ushort* __restrict__ Y) {
    int node = (int)((blockIdx.x * blockDim.x + threadIdx.x) >> 6);
    int lane = threadIdx.x & 63;
    if (node >= N_NODES) return;
    int beg = rowptr[node], deg = rowptr[node + 1] - beg;

    float m, dinv, adiB;
    if (NH == 1) {
        float adi = Ad[node];
        float mm = -1e30f;
        for (int i = lane; i <= deg; i += 64) {
            int src = (i < deg) ? csr[beg + i] : node;
            mm = fmaxf(mm, lrelu(As[src] + adi));
        }
        #pragma unroll
        for (int off = 1; off < 64; off <<= 1) mm = fmaxf(mm, __shfl_xor(mm, off, 64));
        float den = 0.f;
        for (int i = lane; i <= deg; i += 64) {
            int src = (i < deg) ? csr[beg + i] : node;
            den += __expf(lrelu(As[src] + adi) - mm);
        }
        #pragma unroll
        for (int off = 1; off < 64; off <<= 1) den += __shfl_xor(den, off, 64);
        m = mm; dinv = 1.0f / den; adiB = adi;
    } else {
        int h = lane & 3, il = lane >> 2;
        float adi = Ad[(size_t)node * 4 + h];
        float mm = -1e30f;
        for (int i = il; i <= deg; i += 16) {
            int src = (i < deg) ? csr[beg + i] : node;
            mm = fmaxf(mm, lrelu(As[(size_t)src * 4 + h] + adi));
        }
        #pragma unroll
        for (int off = 4; off < 64; off <<= 1) mm = fmaxf(mm, __shfl_xor(mm, off, 64));
        float den = 0.f;
        for (int i = il; i <= deg; i += 16) {
            int src = (i < deg) ? csr[beg + i] : node;
            den += __expf(lrelu(As[(size_t)src * 4 + h] + adi) - mm);
        }
        #pragma unroll
        for (int off = 4; off < 64; off <<= 1) den += __shfl_xor(den, off, 64);
        // remap to phase-B head h' = (lane&15)>>2; lanes 0..3 hold h=0..3
        int hp = (lane & 15) >> 2;
        m = __shfl(mm, hp, 64);
        float denp = __shfl(den, hp, 64);
        dinv = 1.0f / denp;
        adiB = __shfl(adi, hp, 64);
    }

    // Phase B: 16 lanes cover a 256B row; 4 rows per round.
    int sub = lane >> 4;
    int cg = (lane & 15) << 3;
    int hB = (NH == 4) ? ((lane & 15) >> 2) : 0;
    int items = deg + 1;
    float acc[8] = {};
    for (int base = 0; base < items; base += 4) {
        int i = base + sub;
        int src = (i < deg) ? csr[beg + i] : node;
        float e = (NH == 1) ? (As[src] + adiB) : (As[(size_t)src * 4 + hB] + adiB);
        float a = __expf(lrelu(e) - m) * dinv;
        if (i > deg) a = 0.f;
        uint4 rv = *(const uint4*)&XH[(size_t)src * 128 + cg];
        uint rw[4] = { rv.x, rv.y, rv.z, rv.w };
        #pragma unroll
        for (int k = 0; k < 4; ++k) {
            acc[2 * k]     += a * bf2f((ushort)(rw[k] & 0xFFFF));
            acc[2 * k + 1] += a * bf2f((ushort)(rw[k] >> 16));
        }
    }
    #pragma unroll
    for (int k = 0; k < 8; ++k) {
        acc[k] += __shfl_xor(acc[k], 16, 64);
        acc[k] += __shfl_xor(acc[k], 32, 64);
    }
    if (sub == 0) {
        uint o[4];
        #pragma unroll
        for (int k = 0; k < 4; ++k) {
            float v0 = fmaxf(acc[2 * k]     + bias[cg + 2 * k],     0.f);
            float v1 = fmaxf(acc[2 * k + 1] + bias[cg + 2 * k + 1], 0.f);
            o[k] = (uint)f2bf(v0) | ((uint)f2bf(v1) << 16);
        }
        *reinterpret_cast<uint4*>(&Y[(size_t)node * 128 + cg]) = *reinterpret_cast<uint4*>(o);
    }
}

// ---------------- fused softmax + aggregate + log-softmax (layer 3) ----------------
// xh rows: bf16 stride 64 (128B), 40 valid cols. Output: log-softmax'd fp32 [N][40].

__global__ void agg_fused_l3(const ushort* __restrict__ XH, const float* __restrict__ As,
                             const float* __restrict__ Ad, const float* __restrict__ bias,
                             const int* __restrict__ rowptr, const int* __restrict__ csr,
                             float* __restrict__ Y) {
    int node = (int)((blockIdx.x * blockDim.x + threadIdx.x) >> 6);
    int lane = threadIdx.x & 63;
    if (node >= N_NODES) return;
    int beg = rowptr[node], deg = rowptr[node + 1] - beg;
    float adi = Ad[node];

    float mm = -1e30f;
    for (int i = lane; i <= deg; i += 64) {
        int src = (i < deg) ? csr[beg + i] : node;
        mm = fmaxf(mm, lrelu(As[src] + adi));
    }
    #pragma unroll
    for (int off = 1; off < 64; off <<= 1) mm = fmaxf(mm, __shfl_xor(mm, off, 64));
    float den = 0.f;
    for (int i = lane; i <= deg; i += 64) {
        int src = (i < deg) ? csr[beg + i] : node;
        den += __expf(lrelu(As[src] + adi) - mm);
    }
    #pragma unroll
    for (int off = 1; off < 64; off <<= 1) den += __shfl_xor(den, off, 64);
    float dinv = 1.0f / den;

    // Phase B: 8 lanes cover a 128B row; 8 rows per round.
    int sub = lane >> 3;
    int cg = (lane & 7) << 3;
    int items = deg + 1;
    float acc[8] = {};
    for (int base = 0; base < items; base += 8) {
        int i = base + sub;
        int src = (i < deg) ? csr[beg + i] : node;
        float a = __expf(lrelu(As[src] + adi) - mm) * dinv;
        if (i > deg) a = 0.f;
        uint4 rv = *(const uint4*)&XH[(size_t)src * 64 + cg];
        uint rw[4] = { rv.x, rv.y, rv.z, rv.w };
        #pragma unroll
        for (int k = 0; k < 4; ++k) {
            acc[2 * k]     += a * bf2f((ushort)(rw[k] & 0xFFFF));
            acc[2 * k + 1] += a * bf2f((ushort)(rw[k] >> 16));
        }
    }
    #pragma unroll
    for (int k = 0; k < 8; ++k) {
        acc[k] += __shfl_xor(acc[k], 8, 64);
        acc[k] += __shfl_xor(acc[k], 16, 64);
        acc[k] += __shfl_xor(acc[k], 32, 64);
    }
    // lanes 0..4 hold valid col-groups (cg 0..32, 8 cols each = 40 total)
    bool valid = (lane < 5);
    float v[8];
    float pm = -1e30f;
    if (valid) {
        #pragma unroll
        for (int k = 0; k < 8; ++k) {
            v[k] = acc[k] + bias[cg + k];
            pm = fmaxf(pm, v[k]);
        }
    }
    #pragma unroll
    for (int off = 1; off < 8; off <<= 1) pm = fmaxf(pm, __shfl_xor(pm, off, 64));
    float ps = 0.f;
    if (valid) {
        #pragma unroll
        for (int k = 0; k < 8; ++k) ps += __expf(v[k] - pm);
    }
    #pragma unroll
    for (int off = 1; off < 8; off <<= 1) ps += __shfl_xor(ps, off, 64);
    if (valid) {
        float lden = __logf(ps);
        float4 o0 = make_float4(v[0] - pm - lden, v[1] - pm - lden,
                                v[2] - pm - lden, v[3] - pm - lden);
        float4 o1 = make_float4(v[4] - pm - lden, v[5] - pm - lden,
                                v[6] - pm - lden, v[7] - pm - lden);
        *reinterpret_cast<float4*>(&Y[(size_t)node * 40 + cg]) = o0;
        *reinterpret_cast<float4*>(&Y[(size_t)node * 40 + cg + 4]) = o1;
    }
}

// ---------------- launch ----------------

static inline size_t align256(size_t x) { return (x + 255) & ~(size_t)255; }

extern "C" void kernel_launch(void* const* d_in, const int* in_sizes, int n_in,
                              void* d_out, int out_size, void* d_ws, size_t ws_size,
                              hipStream_t stream) {
    const int*   edge = (const int*)d_in[0];
    const float* feat = (const float*)d_in[1];
    const float* W1   = (const float*)d_in[2];
    const float* as1  = (const float*)d_in[3];
    const float* ad1  = (const float*)d_in[4];
    const float* b1   = (const float*)d_in[5];
    const float* W2   = (const float*)d_in[6];
    const float* as2  = (const float*)d_in[7];
    const float* ad2  = (const float*)d_in[8];
    const float* b2   = (const float*)d_in[9];
    const float* W3   = (const float*)d_in[10];
    const float* as3  = (const float*)d_in[11];
    const float* ad3  = (const float*)d_in[12];
    const float* b3   = (const float*)d_in[13];
    float* out = (float*)d_out;

    const int* srcArr = edge;
    const int* dstArr = edge + N_EDGES;

    const size_t NB128 = (size_t)N_NODES * 128 * 2;   // 25.6 MB

    char* w = (char*)d_ws;
    char* regionA = w; w += align256(2 * NB128);      // pairs -> xh2|h2
    char* regionB = w; w += align256(NB128);          // xh1; later xh3 bf16 [100k][64]
    char* regionC = w; w += align256(NB128);          // h1
    float* As   = (float*)w; w += align256((size_t)N_NODES * 4 * 4);
    float* Ad   = (float*)w; w += align256((size_t)N_NODES * 4 * 4);
    int* rowptr = (int*)w;   w += align256((size_t)(N_NODES + 1) * 4);
    int* csr    = (int*)w;   w += align256((size_t)N_EDGES * 4);
    int* chunkCnt  = (int*)w; w += align256((size_t)NCHUNK * NBUCK * 4);
    int* chunkBase = (int*)w; w += align256((size_t)NCHUNK * NBUCK * 4);
    int* bucketBase = (int*)w; w += align256((size_t)(NBUCK + 1) * 4);
    ushort* WT1 = (ushort*)w; w += align256((size_t)128 * 256 * 2);
    ushort* WT2 = (ushort*)w; w += align256((size_t)128 * 128 * 2);
    ushort* WT3 = (ushort*)w; w += align256((size_t)48 * 128 * 2);

    int* pairs = (int*)regionA;                       // packed, dead before xh2

    ushort* xh1 = (ushort*)regionB;                   // [100k][128] bf16
    ushort* h1  = (ushort*)regionC;                   // [100k][128] bf16
    ushort* xh2 = (ushort*)regionA;                   // [100k][128] bf16
    ushort* h2  = (ushort*)(regionA + NB128);         // [100k][128] bf16
    ushort* xh3 = (ushort*)regionB;                   // [100k][64] bf16 (xh1 dead)

    // ---- CSR build ----
    bucket_hist<<<NCHUNK, 256, 0, stream>>>(dstArr, chunkCnt);
    bucket_scan<<<1, 512, 0, stream>>>(chunkCnt, chunkBase, bucketBase);
    bucket_scatter<<<NCHUNK, 256, 0, stream>>>(srcArr, dstArr, chunkBase, bucketBase, pairs);
    bucket_build<<<NBUCK, 256, 0, stream>>>(pairs, bucketBase, rowptr, csr);

    // weights
    transpose_w<<<(128 * 256 + 255) / 256, 256, 0, stream>>>(W1, WT1, 256, 128, 128);
    transpose_w<<<(128 * 128 + 255) / 256, 256, 0, stream>>>(W2, WT2, 128, 128, 128);
    transpose_w<<<(48 * 128 + 255) / 256, 256, 0, stream>>>(W3, WT3, 128, 40, 48);

    int aggGrid = (N_NODES + 3) / 4;
    int gemmGrid = (N_NODES + 63) / 64;

    // ---- layer 1 ----
    mfma_gemm1<<<gemmGrid, 256, 0, stream>>>(feat, WT1, xh1);
    as_ad_bf16<128, 4, 16><<<aggGrid, 256, 0, stream>>>(xh1, as1, ad1, As, Ad);
    agg_fused_bf16<4><<<aggGrid, 256, 0, stream>>>(xh1, As, Ad, b1, rowptr, csr, h1);

    // ---- layer 2 ----
    mfma_gemm_nc128<128><<<gemmGrid, 256, 0, stream>>>(h1, WT2, xh2);
    as_ad_bf16<128, 1, 64><<<aggGrid, 256, 0, stream>>>(xh2, as2, ad2, As, Ad);
    agg_fused_bf16<1><<<aggGrid, 256, 0, stream>>>(xh2, As, Ad, b2, rowptr, csr, h2);

    // ---- layer 3 ----
    mfma_gemm_nc40<<<gemmGrid, 256, 0, stream>>>(h2, WT3, xh3);
    as_ad_w64_40<<<aggGrid, 256, 0, stream>>>(xh3, as3, ad3, As, Ad);
    agg_fused_l3<<<aggGrid, 256, 0, stream>>>(xh3, As, Ad, b3, rowptr, csr, out);
}

// Round 11
// 378.082 us; speedup vs baseline: 2.6867x; 1.1886x over previous
//
#include <hip/hip_runtime.h>
#include <cstdint>

#define N_NODES 100000
#define N_EDGES 1600000
#define NEG_SLOPE 0.2f

#define NBUCK 391          // ceil(100000/256), bucket = dst >> 8
#define NCHUNK 128
#define CHUNK_SZ ((N_EDGES + NCHUNK - 1) / NCHUNK)   // 12500

typedef short s16x8 __attribute__((ext_vector_type(8)));
typedef float f32x4 __attribute__((ext_vector_type(4)));

__device__ inline float bf2f(ushort u) {
    union { uint i; float f; } x; x.i = ((uint)u) << 16; return x.f;
}
__device__ inline ushort f2bf(float f) {
    union { float f; uint i; } x; x.f = f;
    uint r = x.i + 0x7FFF + ((x.i >> 16) & 1);   // RNE
    return (ushort)(r >> 16);
}
__device__ inline float lrelu(float e) { return (e > 0.f) ? e : NEG_SLOPE * e; }

// ---------------- CSR build: 2-level bucket counting sort (packed pairs) ----------------

__global__ __launch_bounds__(256) void bucket_hist(const int* __restrict__ dst,
                                                   int* __restrict__ chunkCnt) {
    __shared__ int cnt[NBUCK];
    int t = threadIdx.x, blk = blockIdx.x;
    for (int b = t; b < NBUCK; b += 256) cnt[b] = 0;
    __syncthreads();
    int beg = blk * CHUNK_SZ, end = min(beg + CHUNK_SZ, N_EDGES);
    for (int i = beg + t; i < end; i += 256) atomicAdd(&cnt[dst[i] >> 8], 1);
    __syncthreads();
    for (int b = t; b < NBUCK; b += 256) chunkCnt[blk * NBUCK + b] = cnt[b];
}

__global__ __launch_bounds__(512) void bucket_scan(const int* __restrict__ chunkCnt,
                                                   int* __restrict__ chunkBase,
                                                   int* __restrict__ bucketBase) {
    __shared__ int tot[512];
    int b = threadIdx.x;
    int run = 0;
    if (b < NBUCK) {
        for (int c = 0; c < NCHUNK; ++c) {
            chunkBase[c * NBUCK + b] = run;
            run += chunkCnt[c * NBUCK + b];
        }
    }
    tot[b] = (b < NBUCK) ? run : 0;
    __syncthreads();
    for (int off = 1; off < 512; off <<= 1) {
        int x = (b >= off) ? tot[b - off] : 0;
        __syncthreads();
        tot[b] += x;
        __syncthreads();
    }
    if (b == 0) bucketBase[0] = 0;
    if (b < NBUCK) bucketBase[b + 1] = tot[b];   // inclusive -> base of b+1
}

// packed pair: (src << 8) | (dst & 255); src < 2^17 so fits.
__global__ __launch_bounds__(256) void bucket_scatter(const int* __restrict__ src,
                                                      const int* __restrict__ dst,
                                                      const int* __restrict__ chunkBase,
                                                      const int* __restrict__ bucketBase,
                                                      int* __restrict__ pairs) {
    __shared__ int cur[NBUCK];
    int t = threadIdx.x, blk = blockIdx.x;
    for (int b = t; b < NBUCK; b += 256)
        cur[b] = bucketBase[b] + chunkBase[blk * NBUCK + b];
    __syncthreads();
    int beg = blk * CHUNK_SZ, end = min(beg + CHUNK_SZ, N_EDGES);
    for (int i = beg + t; i < end; i += 256) {
        int d = dst[i];
        int pos = atomicAdd(&cur[d >> 8], 1);
        pairs[pos] = (src[i] << 8) | (d & 255);
    }
}

__global__ __launch_bounds__(256) void bucket_build(const int* __restrict__ pairs,
                                                    const int* __restrict__ bucketBase,
                                                    int* __restrict__ rowptr,
                                                    int* __restrict__ csr) {
    __shared__ int cnt[256], pre[256];
    int b = blockIdx.x, t = threadIdx.x;
    cnt[t] = 0;
    __syncthreads();
    int beg = bucketBase[b], end = bucketBase[b + 1];
    for (int i = beg + t; i < end; i += 256) atomicAdd(&cnt[pairs[i] & 255], 1);
    __syncthreads();
    int v = cnt[t];
    pre[t] = v;
    __syncthreads();
    for (int off = 1; off < 256; off <<= 1) {
        int x = (t >= off) ? pre[t - off] : 0;
        __syncthreads();
        pre[t] += x;
        __syncthreads();
    }
    int excl = pre[t] - v;
    int node = b * 256 + t;
    if (node <= N_NODES) rowptr[node] = beg + excl;
    cnt[t] = excl;   // reuse as cursor
    __syncthreads();
    for (int i = beg + t; i < end; i += 256) {
        int p = pairs[i];
        int pos = beg + atomicAdd(&cnt[p & 255], 1);
        csr[pos] = p >> 8;
    }
}

// ---------------- weight transpose/convert ----------------
__global__ void transpose_w(const float* __restrict__ W, ushort* __restrict__ BT,
                            int K, int N, int Npad) {
    int i = blockIdx.x * blockDim.x + threadIdx.x;
    if (i >= Npad * K) return;
    int n = i / K, k = i - n * K;
    float v = (n < N) ? W[(size_t)k * N + n] : 0.f;
    BT[i] = f2bf(v);
}

// ---------------- MFMA GEMM layer1: fp32 X (K=256), fused bf16 convert ----------------

__global__ __launch_bounds__(256) void mfma_gemm1(const float* __restrict__ X,
                                                  const ushort* __restrict__ BT,
                                                  ushort* __restrict__ Y) {
    __shared__ ushort As_[64][40];
    __shared__ ushort Bs[128][40];
    int m0 = blockIdx.x * 64;
    int t = threadIdx.x;
    int wave = t >> 6, lane = t & 63;
    int wm = wave >> 1, wn = wave & 1;
    f32x4 acc[2][4] = {};
    for (int kt = 0; kt < 256; kt += 32) {
        {
            int r = t >> 2, kg = (t & 3) << 3;
            int rr = (m0 + r < N_NODES) ? m0 + r : N_NODES - 1;
            float4 xa = *(const float4*)&X[(size_t)rr * 256 + kt + kg];
            float4 xb = *(const float4*)&X[(size_t)rr * 256 + kt + kg + 4];
            ushort o[8] = { f2bf(xa.x), f2bf(xa.y), f2bf(xa.z), f2bf(xa.w),
                            f2bf(xb.x), f2bf(xb.y), f2bf(xb.z), f2bf(xb.w) };
            *(s16x8*)&As_[r][kg] = *(s16x8*)o;
        }
        #pragma unroll
        for (int i = 0; i < 2; ++i) {
            int idx = t + (i << 8);
            int r = idx >> 2, kg = (idx & 3) << 3;
            *(s16x8*)&Bs[r][kg] = *(const s16x8*)&BT[(size_t)r * 256 + kt + kg];
        }
        __syncthreads();
        int row = lane & 15, koff = (lane >> 4) << 3;
        s16x8 a[2], b[4];
        #pragma unroll
        for (int mf = 0; mf < 2; ++mf)
            a[mf] = *(s16x8*)&As_[wm * 32 + mf * 16 + row][koff];
        #pragma unroll
        for (int nf = 0; nf < 4; ++nf)
            b[nf] = *(s16x8*)&Bs[wn * 64 + nf * 16 + row][koff];
        #pragma unroll
        for (int mf = 0; mf < 2; ++mf)
            #pragma unroll
            for (int nf = 0; nf < 4; ++nf)
                acc[mf][nf] = __builtin_amdgcn_mfma_f32_16x16x32_bf16(a[mf], b[nf], acc[mf][nf], 0, 0, 0);
        __syncthreads();
    }
    int colb = lane & 15, rowb = (lane >> 4) << 2;
    #pragma unroll
    for (int mf = 0; mf < 2; ++mf)
        #pragma unroll
        for (int nf = 0; nf < 4; ++nf)
            #pragma unroll
            for (int reg = 0; reg < 4; ++reg) {
                int row = m0 + wm * 32 + mf * 16 + rowb + reg;
                int col = wn * 64 + nf * 16 + colb;
                if (row < N_NODES) Y[(size_t)row * 128 + col] = f2bf(acc[mf][nf][reg]);
            }
}

// ---------------- MFMA GEMM, bf16 in, N=128 out bf16 (layer 2) ----------------

template <int K>
__global__ __launch_bounds__(256) void mfma_gemm_nc128(const ushort* __restrict__ X,
                                                       const ushort* __restrict__ BT,
                                                       ushort* __restrict__ Y) {
    __shared__ ushort As_[64][40];
    __shared__ ushort Bs[128][40];
    int m0 = blockIdx.x * 64;
    int t = threadIdx.x;
    int wave = t >> 6, lane = t & 63;
    int wm = wave >> 1, wn = wave & 1;
    f32x4 acc[2][4] = {};
    for (int kt = 0; kt < K; kt += 32) {
        {
            int r = t >> 2, kg = (t & 3) << 3;
            *(s16x8*)&As_[r][kg] = *(const s16x8*)&X[(size_t)(m0 + r) * K + kt + kg];
        }
        #pragma unroll
        for (int i = 0; i < 2; ++i) {
            int idx = t + (i << 8);
            int r = idx >> 2, kg = (idx & 3) << 3;
            *(s16x8*)&Bs[r][kg] = *(const s16x8*)&BT[(size_t)r * K + kt + kg];
        }
        __syncthreads();
        int row = lane & 15, koff = (lane >> 4) << 3;
        s16x8 a[2], b[4];
        #pragma unroll
        for (int mf = 0; mf < 2; ++mf)
            a[mf] = *(s16x8*)&As_[wm * 32 + mf * 16 + row][koff];
        #pragma unroll
        for (int nf = 0; nf < 4; ++nf)
            b[nf] = *(s16x8*)&Bs[wn * 64 + nf * 16 + row][koff];
        #pragma unroll
        for (int mf = 0; mf < 2; ++mf)
            #pragma unroll
            for (int nf = 0; nf < 4; ++nf)
                acc[mf][nf] = __builtin_amdgcn_mfma_f32_16x16x32_bf16(a[mf], b[nf], acc[mf][nf], 0, 0, 0);
        __syncthreads();
    }
    int colb = lane & 15, rowb = (lane >> 4) << 2;
    #pragma unroll
    for (int mf = 0; mf < 2; ++mf)
        #pragma unroll
        for (int nf = 0; nf < 4; ++nf)
            #pragma unroll
            for (int reg = 0; reg < 4; ++reg) {
                int row = m0 + wm * 32 + mf * 16 + rowb + reg;
                int col = wn * 64 + nf * 16 + colb;
                if (row < N_NODES) Y[(size_t)row * 128 + col] = f2bf(acc[mf][nf][reg]);
            }
}

// ---------------- MFMA GEMM, K=128, N=40 (padded 48), bf16 out stride 64 ----------------

__global__ __launch_bounds__(256) void mfma_gemm_nc40(const ushort* __restrict__ X,
                                                      const ushort* __restrict__ BT,
                                                      ushort* __restrict__ Y) {
    __shared__ ushort As_[64][40];
    __shared__ ushort Bs[48][40];
    int m0 = blockIdx.x * 64;
    int t = threadIdx.x, wave = t >> 6, lane = t & 63;
    f32x4 acc[3] = {};
    for (int kt = 0; kt < 128; kt += 32) {
        {
            int r = t >> 2, kg = (t & 3) << 3;
            *(s16x8*)&As_[r][kg] = *(const s16x8*)&X[(size_t)(m0 + r) * 128 + kt + kg];
        }
        if (t < 192) {
            int r = t >> 2, kg = (t & 3) << 3;
            *(s16x8*)&Bs[r][kg] = *(const s16x8*)&BT[(size_t)r * 128 + kt + kg];
        }
        __syncthreads();
        int row = lane & 15, koff = (lane >> 4) << 3;
        s16x8 a = *(s16x8*)&As_[wave * 16 + row][koff];
        #pragma unroll
        for (int nf = 0; nf < 3; ++nf) {
            s16x8 b = *(s16x8*)&Bs[nf * 16 + row][koff];
            acc[nf] = __builtin_amdgcn_mfma_f32_16x16x32_bf16(a, b, acc[nf], 0, 0, 0);
        }
        __syncthreads();
    }
    int colb = lane & 15, rowb = (lane >> 4) << 2;
    #pragma unroll
    for (int nf = 0; nf < 3; ++nf)
        #pragma unroll
        for (int reg = 0; reg < 4; ++reg) {
            int row = m0 + wave * 16 + rowb + reg;
            int col = nf * 16 + colb;
            if (row < N_NODES) Y[(size_t)row * 64 + col] = f2bf(acc[nf][reg]);
        }
}

// ---------------- attention coefficients ----------------

template <int WD, int NH, int SEG>
__global__ void as_ad_bf16(const ushort* __restrict__ XH, const float* __restrict__ asrc,
                           const float* __restrict__ adst, float* __restrict__ As,
                           float* __restrict__ Ad) {
    int node = (int)((blockIdx.x * blockDim.x + threadIdx.x) >> 6);
    int lane = threadIdx.x & 63;
    if (node >= N_NODES) return;
    int c0 = lane * 2;
    uint xv = *reinterpret_cast<const uint*>(&XH[(size_t)node * WD + c0]);
    float x0 = bf2f((ushort)(xv & 0xFFFF)), x1 = bf2f((ushort)(xv >> 16));
    float2 a = *reinterpret_cast<const float2*>(&asrc[c0]);
    float2 b = *reinterpret_cast<const float2*>(&adst[c0]);
    float s = x0 * a.x + x1 * a.y;
    float d = x0 * b.x + x1 * b.y;
    #pragma unroll
    for (int off = 1; off < SEG; off <<= 1) {
        s += __shfl_xor(s, off, 64);
        d += __shfl_xor(d, off, 64);
    }
    if ((lane % SEG) == 0) {
        int h = c0 / (WD / NH);
        As[(size_t)node * NH + h] = s;
        Ad[(size_t)node * NH + h] = d;
    }
}

// layer 3: rows stride 64 bf16, 40 valid cols.
__global__ void as_ad_w64_40(const ushort* __restrict__ XH, const float* __restrict__ asrc,
                             const float* __restrict__ adst, float* __restrict__ As,
                             float* __restrict__ Ad) {
    int node = (int)((blockIdx.x * blockDim.x + threadIdx.x) >> 6);
    int lane = threadIdx.x & 63;
    if (node >= N_NODES) return;
    int c0 = lane * 2;
    float s = 0.f, d = 0.f;
    if (c0 < 40) {
        uint xv = *reinterpret_cast<const uint*>(&XH[(size_t)node * 64 + c0]);
        float x0 = bf2f((ushort)(xv & 0xFFFF)), x1 = bf2f((ushort)(xv >> 16));
        float2 a = *reinterpret_cast<const float2*>(&asrc[c0]);
        float2 b = *reinterpret_cast<const float2*>(&adst[c0]);
        s = x0 * a.x + x1 * a.y;
        d = x0 * b.x + x1 * b.y;
    }
    #pragma unroll
    for (int off = 1; off < 64; off <<= 1) {
        s += __shfl_xor(s, off, 64);
        d += __shfl_xor(d, off, 64);
    }
    if (lane == 0) { As[node] = s; Ad[node] = d; }
}

// ---------------- single-pass aggregate (WD=128 bf16) ----------------
// out = sum_j exp(e_j) x_j / sum_j exp(e_j)  -- no max shift (|e| < ~10, fp32-safe).
// 16 lanes cover a 256B row; 4 rows per round; acc + den reduced via shfl at end.

template <int NH>
__global__ void agg_fused_bf16(const ushort* __restrict__ XH, const float* __restrict__ As,
                               const float* __restrict__ Ad, const float* __restrict__ bias,
                               const int* __restrict__ rowptr, const int* __restrict__ csr,
                               ushort* __restrict__ Y) {
    int node = (int)((blockIdx.x * blockDim.x + threadIdx.x) >> 6);
    int lane = threadIdx.x & 63;
    if (node >= N_NODES) return;
    int sub = lane >> 4;            // 0..3: row within round
    int cg = (lane & 15) << 3;      // col group: 8 bf16 = 16B
    int hB = (NH == 4) ? ((lane & 15) >> 2) : 0;
    float adiB = Ad[(size_t)node * NH + hB];
    int beg = rowptr[node], deg = rowptr[node + 1] - beg;
    int items = deg + 1;            // + self loop
    float acc[8] = {};
    float den = 0.f;
    for (int base = 0; base < items; base += 4) {
        int i = base + sub;
        int src = (i < deg) ? csr[beg + i] : node;
        float e = As[(size_t)src * NH + hB] + adiB;
        float a = __expf(lrelu(e));
        if (i > deg) a = 0.f;
        den += a;
        uint4 rv = *(const uint4*)&XH[(size_t)src * 128 + cg];
        uint rw[4] = { rv.x, rv.y, rv.z, rv.w };
        #pragma unroll
        for (int k = 0; k < 4; ++k) {
            acc[2 * k]     += a * bf2f((ushort)(rw[k] & 0xFFFF));
            acc[2 * k + 1] += a * bf2f((ushort)(rw[k] >> 16));
        }
    }
    den += __shfl_xor(den, 16, 64);
    den += __shfl_xor(den, 32, 64);
    #pragma unroll
    for (int k = 0; k < 8; ++k) {
        acc[k] += __shfl_xor(acc[k], 16, 64);
        acc[k] += __shfl_xor(acc[k], 32, 64);
    }
    if (sub == 0) {                 // lanes 0..15 write cols cg..cg+7
        float dinv = 1.0f / den;
        uint o[4];
        #pragma unroll
        for (int k = 0; k < 4; ++k) {
            float v0 = fmaxf(acc[2 * k]     * dinv + bias[cg + 2 * k],     0.f);
            float v1 = fmaxf(acc[2 * k + 1] * dinv + bias[cg + 2 * k + 1], 0.f);
            o[k] = (uint)f2bf(v0) | ((uint)f2bf(v1) << 16);
        }
        *reinterpret_cast<uint4*>(&Y[(size_t)node * 128 + cg]) = *reinterpret_cast<uint4*>(o);
    }
}

// ---------------- single-pass aggregate + log-softmax (layer 3) ----------------
// xh rows: bf16 stride 64 (128B), 40 valid cols. Output: log-softmax'd fp32 [N][40].

__global__ void agg_fused_l3(const ushort* __restrict__ XH, const float* __restrict__ As,
                             const float* __restrict__ Ad, const float* __restrict__ bias,
                             const int* __restrict__ rowptr, const int* __restrict__ csr,
                             float* __restrict__ Y) {
    int node = (int)((blockIdx.x * blockDim.x + threadIdx.x) >> 6);
    int lane = threadIdx.x & 63;
    if (node >= N_NODES) return;
    int sub = lane >> 3;            // 0..7: row within round
    int cg = (lane & 7) << 3;       // col group: 8 bf16 = 16B
    float adi = Ad[node];
    int beg = rowptr[node], deg = rowptr[node + 1] - beg;
    int items = deg + 1;
    float acc[8] = {};
    float den = 0.f;
    for (int base = 0; base < items; base += 8) {
        int i = base + sub;
        int src = (i < deg) ? csr[beg + i] : node;
        float a = __expf(lrelu(As[src] + adi));
        if (i > deg) a = 0.f;
        den += a;
        uint4 rv = *(const uint4*)&XH[(size_t)src * 64 + cg];
        uint rw[4] = { rv.x, rv.y, rv.z, rv.w };
        #pragma unroll
        for (int k = 0; k < 4; ++k) {
            acc[2 * k]     += a * bf2f((ushort)(rw[k] & 0xFFFF));
            acc[2 * k + 1] += a * bf2f((ushort)(rw[k] >> 16));
        }
    }
    den += __shfl_xor(den, 8, 64);
    den += __shfl_xor(den, 16, 64);
    den += __shfl_xor(den, 32, 64);
    #pragma unroll
    for (int k = 0; k < 8; ++k) {
        acc[k] += __shfl_xor(acc[k], 8, 64);
        acc[k] += __shfl_xor(acc[k], 16, 64);
        acc[k] += __shfl_xor(acc[k], 32, 64);
    }
    // lanes 0..4 hold valid col-groups (cg 0..32, 8 cols each = 40 total)
    bool valid = (lane < 5);
    float v[8];
    float pm = -1e30f;
    if (valid) {
        float dinv = 1.0f / den;
        #pragma unroll
        for (int k = 0; k < 8; ++k) {
            v[k] = acc[k] * dinv + bias[cg + k];
            pm = fmaxf(pm, v[k]);
        }
    }
    #pragma unroll
    for (int off = 1; off < 8; off <<= 1) pm = fmaxf(pm, __shfl_xor(pm, off, 64));
    float ps = 0.f;
    if (valid) {
        #pragma unroll
        for (int k = 0; k < 8; ++k) ps += __expf(v[k] - pm);
    }
    #pragma unroll
    for (int off = 1; off < 8; off <<= 1) ps += __shfl_xor(ps, off, 64);
    if (valid) {
        float lden = __logf(ps);
        float4 o0 = make_float4(v[0] - pm - lden, v[1] - pm - lden,
                                v[2] - pm - lden, v[3] - pm - lden);
        float4 o1 = make_float4(v[4] - pm - lden, v[5] - pm - lden,
                                v[6] - pm - lden, v[7] - pm - lden);
        *reinterpret_cast<float4*>(&Y[(size_t)node * 40 + cg]) = o0;
        *reinterpret_cast<float4*>(&Y[(size_t)node * 40 + cg + 4]) = o1;
    }
}

// ---------------- launch ----------------

static inline size_t align256(size_t x) { return (x + 255) & ~(size_t)255; }

extern "C" void kernel_launch(void* const* d_in, const int* in_sizes, int n_in,
                              void* d_out, int out_size, void* d_ws, size_t ws_size,
                              hipStream_t stream) {
    const int*   edge = (const int*)d_in[0];
    const float* feat = (const float*)d_in[1];
    const float* W1   = (const float*)d_in[2];
    const float* as1  = (const float*)d_in[3];
    const float* ad1  = (const float*)d_in[4];
    const float* b1   = (const float*)d_in[5];
    const float* W2   = (const float*)d_in[6];
    const float* as2  = (const float*)d_in[7];
    const float* ad2  = (const float*)d_in[8];
    const float* b2   = (const float*)d_in[9];
    const float* W3   = (const float*)d_in[10];
    const float* as3  = (const float*)d_in[11];
    const float* ad3  = (const float*)d_in[12];
    const float* b3   = (const float*)d_in[13];
    float* out = (float*)d_out;

    const int* srcArr = edge;
    const int* dstArr = edge + N_EDGES;

    const size_t NB128 = (size_t)N_NODES * 128 * 2;   // 25.6 MB

    char* w = (char*)d_ws;
    char* regionA = w; w += align256(2 * NB128);      // pairs -> xh2|h2
    char* regionB = w; w += align256(NB128);          // xh1; later xh3 bf16 [100k][64]
    char* regionC = w; w += align256(NB128);          // h1
    float* As   = (float*)w; w += align256((size_t)N_NODES * 4 * 4);
    float* Ad   = (float*)w; w += align256((size_t)N_NODES * 4 * 4);
    int* rowptr = (int*)w;   w += align256((size_t)(N_NODES + 1) * 4);
    int* csr    = (int*)w;   w += align256((size_t)N_EDGES * 4);
    int* chunkCnt  = (int*)w; w += align256((size_t)NCHUNK * NBUCK * 4);
    int* chunkBase = (int*)w; w += align256((size_t)NCHUNK * NBUCK * 4);
    int* bucketBase = (int*)w; w += align256((size_t)(NBUCK + 1) * 4);
    ushort* WT1 = (ushort*)w; w += align256((size_t)128 * 256 * 2);
    ushort* WT2 = (ushort*)w; w += align256((size_t)128 * 128 * 2);
    ushort* WT3 = (ushort*)w; w += align256((size_t)48 * 128 * 2);

    int* pairs = (int*)regionA;                       // packed, dead before xh2

    ushort* xh1 = (ushort*)regionB;                   // [100k][128] bf16
    ushort* h1  = (ushort*)regionC;                   // [100k][128] bf16
    ushort* xh2 = (ushort*)regionA;                   // [100k][128] bf16
    ushort* h2  = (ushort*)(regionA + NB128);         // [100k][128] bf16
    ushort* xh3 = (ushort*)regionB;                   // [100k][64] bf16 (xh1 dead)

    // ---- CSR build ----
    bucket_hist<<<NCHUNK, 256, 0, stream>>>(dstArr, chunkCnt);
    bucket_scan<<<1, 512, 0, stream>>>(chunkCnt, chunkBase, bucketBase);
    bucket_scatter<<<NCHUNK, 256, 0, stream>>>(srcArr, dstArr, chunkBase, bucketBase, pairs);
    bucket_build<<<NBUCK, 256, 0, stream>>>(pairs, bucketBase, rowptr, csr);

    // weights
    transpose_w<<<(128 * 256 + 255) / 256, 256, 0, stream>>>(W1, WT1, 256, 128, 128);
    transpose_w<<<(128 * 128 + 255) / 256, 256, 0, stream>>>(W2, WT2, 128, 128, 128);
    transpose_w<<<(48 * 128 + 255) / 256, 256, 0, stream>>>(W3, WT3, 128, 40, 48);

    int aggGrid = (N_NODES + 3) / 4;
    int gemmGrid = (N_NODES + 63) / 64;

    // ---- layer 1 ----
    mfma_gemm1<<<gemmGrid, 256, 0, stream>>>(feat, WT1, xh1);
    as_ad_bf16<128, 4, 16><<<aggGrid, 256, 0, stream>>>(xh1, as1, ad1, As, Ad);
    agg_fused_bf16<4><<<aggGrid, 256, 0, stream>>>(xh1, As, Ad, b1, rowptr, csr, h1);

    // ---- layer 2 ----
    mfma_gemm_nc128<128><<<gemmGrid, 256, 0, stream>>>(h1, WT2, xh2);
    as_ad_bf16<128, 1, 64><<<aggGrid, 256, 0, stream>>>(xh2, as2, ad2, As, Ad);
    agg_fused_bf16<1><<<aggGrid, 256, 0, stream>>>(xh2, As, Ad, b2, rowptr, csr, h2);

    // ---- layer 3 ----
    mfma_gemm_nc40<<<gemmGrid, 256, 0, stream>>>(h2, WT3, xh3);
    as_ad_w64_40<<<aggGrid, 256, 0, stream>>>(xh3, as3, ad3, As, Ad);
    agg_fused_l3<<<aggGrid, 256, 0, stream>>>(xh3, As, Ad, b3, rowptr, csr, out);
}